// Round 7
// baseline (4645.465 us; speedup 1.0000x reference)
//
#include <hip/hip_runtime.h>
#include <hip/hip_bf16.h>

#define NN   50000
#define NE   800000
#define NEP  850000   // NE + NN self loops
#define NG   64
#define DOUT 10

// monotonic float<->uint encoding for atomicMax on signed floats
__device__ inline unsigned fenc(float f) {
    unsigned u = __float_as_uint(f);
    return (u & 0x80000000u) ? ~u : (u | 0x80000000u);
}
__device__ inline float fdec(unsigned u) {
    unsigned b = (u & 0x80000000u) ? (u & 0x7FFFFFFFu) : ~u;
    return __uint_as_float(b);
}
__device__ inline void edge_sd(const int* __restrict__ ei, int e, int& s, int& d) {
    if (e < NE) { s = ei[e]; d = ei[NE + e]; }   // edge_index[0]=src, [1]=dst
    else        { s = e - NE; d = s; }            // self loop
}

// ---------------------------------------------------------------- h0 = x@A_W + A_b -> f32 [NN,64]
__global__ __launch_bounds__(256) void k_lin0f(const float* __restrict__ x,
                                               const float* __restrict__ W,
                                               const float* __restrict__ b,
                                               float* __restrict__ out) {
    int idx = blockIdx.x * 256 + threadIdx.x;   // grid exactly NN*64
    int n = idx >> 6, c = idx & 63;
    if (n >= NN) return;
    float acc = b[c];
    #pragma unroll
    for (int k = 0; k < 16; ++k) acc = fmaf(x[n * 16 + k], W[k * 64 + c], acc);
    out[idx] = acc;
}

// ---------------------------------------------------------------- hB[n,j] = sum_k hA[n,k] W[k,j]
template <int K>
__global__ __launch_bounds__(256) void k_proj(const float* __restrict__ h,
                                              const float* __restrict__ W,
                                              float* __restrict__ o) {
    int idx = blockIdx.x * 256 + threadIdx.x;   // grid exactly NN*256
    int n = idx >> 8, j = idx & 255;
    if (n >= NN) return;
    const float* hr = h + n * K;
    const float* wc = W + j;                     // column j, stride 256
    float acc = 0.f;
    for (int k = 0; k < K; ++k) acc = fmaf(hr[k], wc[k * 256], acc);
    o[idx] = acc;
}

// ---------------------------------------------------------------- ss/sd[n,h]
__global__ __launch_bounds__(256) void k_scoresN(const float* __restrict__ hl,
                                                 const float* __restrict__ a_s,
                                                 const float* __restrict__ a_d,
                                                 float* __restrict__ ss,
                                                 float* __restrict__ sd) {
    int idx = blockIdx.x * 256 + threadIdx.x;
    if (idx >= NN * 4) return;
    int n = idx >> 2, h = idx & 3;
    const float* hr = hl + n * 256 + h * 64;
    const float* sv = a_s + h * 64;
    const float* dv = a_d + h * 64;
    float a = 0.f, b = 0.f;
    for (int c = 0; c < 64; ++c) { float v = hr[c]; a = fmaf(v, sv[c], a); b = fmaf(v, dv[c], b); }
    ss[idx] = a; sd[idx] = b;
}

// ---------------------------------------------------------------- pass 1: segment_max(e, dst)
__global__ __launch_bounds__(256) void k_emax(const int* __restrict__ ei,
                                              const float* __restrict__ ss,
                                              const float* __restrict__ sd,
                                              unsigned* __restrict__ menc) {
    int idx = blockIdx.x * 256 + threadIdx.x;
    if (idx >= NEP * 4) return;
    int e = idx >> 2, h = idx & 3;
    int s, d; edge_sd(ei, e, s, d);
    float sc = ss[s * 4 + h] + sd[d * 4 + h];
    sc = (sc > 0.f) ? sc : 0.2f * sc;            // leaky_relu 0.2
    atomicMax(&menc[d * 4 + h], fenc(sc));
}

// ---------------------------------------------------------------- pass 2: denom = segment_sum(exp(e-m))
__global__ __launch_bounds__(256) void k_esum(const int* __restrict__ ei,
                                              const float* __restrict__ ss,
                                              const float* __restrict__ sd,
                                              const unsigned* __restrict__ menc,
                                              float* __restrict__ den) {
    int idx = blockIdx.x * 256 + threadIdx.x;
    if (idx >= NEP * 4) return;
    int e = idx >> 2, h = idx & 3;
    int s, d; edge_sd(ei, e, s, d);
    float sc = ss[s * 4 + h] + sd[d * 4 + h];
    sc = (sc > 0.f) ? sc : 0.2f * sc;
    float m = fdec(menc[d * 4 + h]);
    atomicAdd(&den[d * 4 + h], __expf(sc - m));
}

// ---------------------------------------------------------------- pass 3: out[dst] += alpha * h[src]
template <int CONCAT>
__global__ __launch_bounds__(256) void k_eacc(const int* __restrict__ ei,
                                              const float* __restrict__ ss,
                                              const float* __restrict__ sd,
                                              const unsigned* __restrict__ menc,
                                              const float* __restrict__ den,
                                              const float* __restrict__ hl,
                                              float* __restrict__ out) {
    int e = blockIdx.x;                          // grid exactly NEP
    int h = threadIdx.x >> 6, c = threadIdx.x & 63;
    int s, d; edge_sd(ei, e, s, d);
    float sc = ss[s * 4 + h] + sd[d * 4 + h];
    sc = (sc > 0.f) ? sc : 0.2f * sc;
    float m = fdec(menc[d * 4 + h]);
    float p = __expf(sc - m) / den[d * 4 + h];   // alpha
    float v = p * hl[s * 256 + h * 64 + c];
    if (CONCAT) atomicAdd(&out[d * 256 + h * 64 + c], v);
    else        atomicAdd(&out[d * 64 + c], 0.25f * v);
}

// ---------------------------------------------------------------- epilogue: +bias (+elu for CONCAT layers)
template <int CONCAT>
__global__ __launch_bounds__(256) void k_post(float* __restrict__ a,
                                              const float* __restrict__ bias) {
    int idx = blockIdx.x * 256 + threadIdx.x;
    if (CONCAT) {
        if (idx >= NN * 256) return;
        float o = a[idx] + bias[idx & 255];
        a[idx] = (o > 0.f) ? o : (__expf(o) - 1.f);   // elu
    } else {
        if (idx >= NN * 64) return;
        a[idx] += bias[idx & 63];
    }
}

// ---------------------------------------------------------------- mean pool accumulation (pool/cnt zeroed)
__global__ __launch_bounds__(256) void k_pool(const float* __restrict__ h,
                                              const int* __restrict__ batch,
                                              float* __restrict__ pool,
                                              float* __restrict__ cnt) {
    int idx = blockIdx.x * 256 + threadIdx.x;   // grid exactly NN*64
    int n = idx >> 6, c = idx & 63;
    if (n >= NN) return;
    int b = batch[n];
    atomicAdd(&pool[b * 64 + c], h[idx]);
    if (c == 0) atomicAdd(&cnt[b], 1.f);
}

// ---------------------------------------------------------------- MLP head (single block), FP32 out
__global__ __launch_bounds__(256) void k_mlp(const float* __restrict__ pool,
                                             const float* __restrict__ cnt,
                                             const float* __restrict__ M0W,
                                             const float* __restrict__ M0b,
                                             const float* __restrict__ M1W,
                                             const float* __restrict__ M1b,
                                             float* __restrict__ out) {
    __shared__ float g[64][64];
    __shared__ float t1[64][64];
    int tid = threadIdx.x;
    for (int idx = tid; idx < 4096; idx += 256) {
        int i = idx >> 6;
        g[i][idx & 63] = pool[idx] / fmaxf(cnt[i], 1.f);
    }
    __syncthreads();
    for (int idx = tid; idx < 4096; idx += 256) {
        int i = idx >> 6, j = idx & 63;
        float acc = M0b[j];
        for (int k = 0; k < 64; ++k) acc = fmaf(g[i][k], M0W[k * 64 + j], acc);
        t1[i][j] = fmaxf(acc, 0.f);
    }
    __syncthreads();
    for (int idx = tid; idx < NG * DOUT; idx += 256) {
        int i = idx / DOUT, j = idx % DOUT;
        float acc = M1b[j];
        for (int k = 0; k < 64; ++k) acc = fmaf(t1[i][k], M1W[k * DOUT + j], acc);
        out[idx] = acc;    // fp32 output — the reference's output dtype is float32
    }
}

extern "C" void kernel_launch(void* const* d_in, const int* in_sizes, int n_in,
                              void* d_out, int out_size, void* d_ws, size_t ws_size,
                              hipStream_t stream) {
    const float* x   = (const float*)d_in[0];
    const int*   ei  = (const int*)d_in[1];
    const int*   bat = (const int*)d_in[2];
    const float* A_W = (const float*)d_in[3];
    const float* A_b = (const float*)d_in[4];
    const float* W0  = (const float*)d_in[5];
    const float* as0 = (const float*)d_in[6];
    const float* ad0 = (const float*)d_in[7];
    const float* b0  = (const float*)d_in[8];
    const float* W1  = (const float*)d_in[9];
    const float* as1 = (const float*)d_in[10];
    const float* ad1 = (const float*)d_in[11];
    const float* b1  = (const float*)d_in[12];
    const float* W2  = (const float*)d_in[13];
    const float* as2 = (const float*)d_in[14];
    const float* ad2 = (const float*)d_in[15];
    const float* b2  = (const float*)d_in[16];
    const float* M0W = (const float*)d_in[17];
    const float* M0b = (const float*)d_in[18];
    const float* M1W = (const float*)d_in[19];
    const float* M1b = (const float*)d_in[20];

    char* ws = (char*)d_ws;
    float*    hA   = (float*)   (ws);                // 51.2 MB f32 [NN,256]
    float*    hB   = (float*)   (ws + 51200000);     // 51.2 MB f32 [NN,256]
    float*    ss   = (float*)   (ws + 102400000);    // [NN,4]
    float*    sd   = (float*)   (ws + 103200000);    // [NN,4]
    unsigned* menc = (unsigned*)(ws + 104000000);    // [NN,4]
    float*    den  = (float*)   (ws + 104800000);    // [NN,4]
    float*    pool = (float*)   (ws + 105600000);    // [NG,64]
    float*    cnt  = (float*)   (ws + 105616384);    // [NG]

    const int GE  = (NEP * 4 + 255) / 256;
    const int GN4 = (NN * 4 + 255) / 256;

    k_lin0f<<<(NN * 64) / 256, 256, 0, stream>>>(x, A_W, A_b, hA);

    // ---- layer 0 (K=64, concat+elu) ----
    k_proj<64><<<(NN * 256) / 256, 256, 0, stream>>>(hA, W0, hB);
    k_scoresN<<<GN4, 256, 0, stream>>>(hB, as0, ad0, ss, sd);
    hipMemsetAsync(hA, 0, NN * 256 * 4, stream);
    hipMemsetAsync(menc, 0, NN * 4 * 4, stream);
    hipMemsetAsync(den, 0, NN * 4 * 4, stream);
    k_emax<<<GE, 256, 0, stream>>>(ei, ss, sd, menc);
    k_esum<<<GE, 256, 0, stream>>>(ei, ss, sd, menc, den);
    k_eacc<1><<<NEP, 256, 0, stream>>>(ei, ss, sd, menc, den, hB, hA);
    k_post<1><<<(NN * 256) / 256, 256, 0, stream>>>(hA, b0);

    // ---- layer 1 (K=256, concat+elu) ----
    k_proj<256><<<(NN * 256) / 256, 256, 0, stream>>>(hA, W1, hB);
    k_scoresN<<<GN4, 256, 0, stream>>>(hB, as1, ad1, ss, sd);
    hipMemsetAsync(hA, 0, NN * 256 * 4, stream);
    hipMemsetAsync(menc, 0, NN * 4 * 4, stream);
    hipMemsetAsync(den, 0, NN * 4 * 4, stream);
    k_emax<<<GE, 256, 0, stream>>>(ei, ss, sd, menc);
    k_esum<<<GE, 256, 0, stream>>>(ei, ss, sd, menc, den);
    k_eacc<1><<<NEP, 256, 0, stream>>>(ei, ss, sd, menc, den, hB, hA);
    k_post<1><<<(NN * 256) / 256, 256, 0, stream>>>(hA, b1);

    // ---- layer 2 (K=256, head-mean) ----
    k_proj<256><<<(NN * 256) / 256, 256, 0, stream>>>(hA, W2, hB);
    k_scoresN<<<GN4, 256, 0, stream>>>(hB, as2, ad2, ss, sd);
    hipMemsetAsync(hA, 0, NN * 64 * 4, stream);
    hipMemsetAsync(menc, 0, NN * 4 * 4, stream);
    hipMemsetAsync(den, 0, NN * 4 * 4, stream);
    k_emax<<<GE, 256, 0, stream>>>(ei, ss, sd, menc);
    k_esum<<<GE, 256, 0, stream>>>(ei, ss, sd, menc, den);
    k_eacc<0><<<NEP, 256, 0, stream>>>(ei, ss, sd, menc, den, hB, hA);
    k_post<0><<<(NN * 64) / 256, 256, 0, stream>>>(hA, b2);

    // ---- pooling + MLP head ----
    hipMemsetAsync(pool, 0, (NG * 64 + NG) * 4, stream);
    k_pool<<<(NN * 64) / 256, 256, 0, stream>>>(hA, bat, pool, cnt);
    k_mlp<<<1, 256, 0, stream>>>(pool, cnt, M0W, M0b, M1W, M1b, (float*)d_out);
}

// Round 8
// 1532.708 us; speedup vs baseline: 3.0309x; 3.0309x over previous
//
#include <hip/hip_runtime.h>
#include <hip/hip_bf16.h>

#define NN   50000
#define NE   800000
#define NEP  850000   // NE + NN self loops
#define NG   64
#define HH   256      // 4 heads * 64 ch
#define DOUT 10

// ---------------------------------------------------------------- h0 = x@A_W + A_b -> f32 [NN,64]
__global__ __launch_bounds__(256) void k_lin0f(const float* __restrict__ x,
                                               const float* __restrict__ W,
                                               const float* __restrict__ b,
                                               float* __restrict__ out) {
    int idx = blockIdx.x * 256 + threadIdx.x;   // grid exactly NN*64
    int n = idx >> 6, c = idx & 63;
    if (n >= NN) return;
    float acc = b[c];
    #pragma unroll
    for (int k = 0; k < 16; ++k) acc = fmaf(x[n * 16 + k], W[k * 64 + c], acc);
    out[idx] = acc;
}

// ---------------------------------------------------------------- degree histogram (deg passed zeroed)
__global__ __launch_bounds__(256) void k_degree(const int* __restrict__ ei, int* __restrict__ deg) {
    int e = blockIdx.x * 256 + threadIdx.x;
    if (e >= NEP) return;
    int dst = (e < NE) ? ei[NE + e] : (e - NE);
    atomicAdd(&deg[dst], 1);
}

// ---------------------------------------------------------------- exclusive scan, 1 block x 256 thr
__global__ __launch_bounds__(256) void k_scan(const int* __restrict__ deg, int* __restrict__ row_ptr) {
    __shared__ int psum[256];
    const int CH = 196;                 // 256*196 = 50176 >= NN
    int tid = threadIdx.x;
    int lo = tid * CH;
    int hi = lo + CH; if (hi > NN) hi = NN;
    int s = 0;
    for (int i = lo; i < hi; ++i) s += deg[i];
    psum[tid] = s;
    __syncthreads();
    if (tid == 0) {
        int run = 0;
        for (int i = 0; i < 256; ++i) { int v = psum[i]; psum[i] = run; run += v; }
    }
    __syncthreads();
    int run = psum[tid];
    for (int i = lo; i < hi; ++i) { row_ptr[i] = run; run += deg[i]; }
    if (tid == 255) row_ptr[NN] = run;
}

// ---------------------------------------------------------------- CSR scatter (cursor passed zeroed)
__global__ __launch_bounds__(256) void k_scatter(const int* __restrict__ ei,
                                                 const int* __restrict__ row_ptr,
                                                 int* __restrict__ cursor,
                                                 int* __restrict__ col_idx) {
    int e = blockIdx.x * 256 + threadIdx.x;
    if (e >= NEP) return;
    int src, dst;
    if (e < NE) { src = ei[e]; dst = ei[NE + e]; }
    else        { src = e - NE; dst = e - NE; }
    int pos = atomicAdd(&cursor[dst], 1);
    col_idx[row_ptr[dst] + pos] = src;
}

// ---------------------------------------------------------------- C[NN,256] = A[NN,K] @ B[K,256], tiled
template <int K>
__global__ __launch_bounds__(256) void k_gemm(const float* __restrict__ A,
                                              const float* __restrict__ B,
                                              float* __restrict__ C) {
    __shared__ float As[16][64];
    __shared__ float Bs[16][64];
    int tid = threadIdx.x;
    int tx = tid & 15, ty = tid >> 4;
    int m0 = blockIdx.x * 64, n0 = blockIdx.y * 64;
    float acc[4][4] = {};
    for (int k0 = 0; k0 < K; k0 += 16) {
        {   // stage A 64x16, transposed into As[k][m]
            int r = tid >> 2;
            int c = (tid & 3) << 2;
            int gr = m0 + r; if (gr >= NN) gr = NN - 1;
            const float4 a4 = *reinterpret_cast<const float4*>(&A[gr * K + k0 + c]);
            As[c + 0][r] = a4.x; As[c + 1][r] = a4.y; As[c + 2][r] = a4.z; As[c + 3][r] = a4.w;
        }
        {   // stage B 16x64
            int r = tid >> 4;
            int c = (tid & 15) << 2;
            *reinterpret_cast<float4*>(&Bs[r][c]) =
                *reinterpret_cast<const float4*>(&B[(k0 + r) * HH + n0 + c]);
        }
        __syncthreads();
        #pragma unroll
        for (int kk = 0; kk < 16; ++kk) {
            float4 a4 = *reinterpret_cast<const float4*>(&As[kk][ty << 2]);
            float4 b4 = *reinterpret_cast<const float4*>(&Bs[kk][tx << 2]);
            float av[4] = {a4.x, a4.y, a4.z, a4.w};
            float bv[4] = {b4.x, b4.y, b4.z, b4.w};
            #pragma unroll
            for (int i = 0; i < 4; ++i)
                #pragma unroll
                for (int j = 0; j < 4; ++j)
                    acc[i][j] = fmaf(av[i], bv[j], acc[i][j]);
        }
        __syncthreads();
    }
    #pragma unroll
    for (int i = 0; i < 4; ++i) {
        int m = m0 + (ty << 2) + i;
        if (m < NN) {
            float4 o = make_float4(acc[i][0], acc[i][1], acc[i][2], acc[i][3]);
            *reinterpret_cast<float4*>(&C[m * HH + n0 + (tx << 2)]) = o;
        }
    }
}

// ---------------------------------------------------------------- ss/sd[n][h] (1 wave/node, shuffle reduce)
__global__ __launch_bounds__(256) void k_scores(const float* __restrict__ hlin,
                                                const float* __restrict__ a_s,
                                                const float* __restrict__ a_d,
                                                float* __restrict__ ss,
                                                float* __restrict__ sd) {
    int wid = threadIdx.x >> 6, lane = threadIdx.x & 63;
    int n = blockIdx.x * 4 + wid;
    if (n >= NN) return;
    float accs[4], accd[4];
    #pragma unroll
    for (int j = 0; j < 4; ++j) {
        float hv = hlin[n * HH + (j << 6) + lane];
        accs[j] = hv * a_s[(j << 6) + lane];
        accd[j] = hv * a_d[(j << 6) + lane];
    }
    #pragma unroll
    for (int d = 1; d < 64; d <<= 1) {
        #pragma unroll
        for (int j = 0; j < 4; ++j) {
            accs[j] += __shfl_xor(accs[j], d, 64);
            accd[j] += __shfl_xor(accd[j], d, 64);
        }
    }
    if (lane == 0) {
        #pragma unroll
        for (int j = 0; j < 4; ++j) { ss[n * 4 + j] = accs[j]; sd[n * 4 + j] = accd[j]; }
    }
}

// ---------------------------------------------------------------- per-node online-softmax aggregation (no atomics)
// MODE 0: concat + bias + elu -> [NN,256];  MODE 1: head-mean + bias -> [NN,64]
template <int MODE>
__global__ __launch_bounds__(256) void k_agg(const float* __restrict__ hlin,
                                             const float* __restrict__ ss,
                                             const float* __restrict__ sd,
                                             const int* __restrict__ row_ptr,
                                             const int* __restrict__ col_idx,
                                             const float* __restrict__ bias,
                                             float* __restrict__ out) {
    int n = blockIdx.x;
    int wid = threadIdx.x >> 6, lane = threadIdx.x & 63;  // wave = head, lane = channel
    int rs = row_ptr[n], re = row_ptr[n + 1];
    float sdn = sd[n * 4 + wid];
    // first edge (self-loop guarantees re > rs)
    int sn = col_idx[rs];
    float sc = ss[sn * 4 + wid] + sdn;
    sc = (sc > 0.f) ? sc : 0.2f * sc;                     // leaky_relu 0.2
    float m = sc, s = 1.f;
    float acc = hlin[sn * HH + (wid << 6) + lane];
    for (int e = rs + 1; e < re; ++e) {
        sn = col_idx[e];
        sc = ss[sn * 4 + wid] + sdn;
        sc = (sc > 0.f) ? sc : 0.2f * sc;
        float hv = hlin[sn * HH + (wid << 6) + lane];
        float mn = fmaxf(m, sc);
        float corr = __expf(m - mn);
        float p = __expf(sc - mn);
        s = s * corr + p;
        acc = acc * corr + p * hv;
        m = mn;
    }
    float o = acc / s;
    if (MODE == 0) {
        o += bias[(wid << 6) + lane];
        o = (o > 0.f) ? o : (__expf(o) - 1.f);            // elu
        out[n * HH + (wid << 6) + lane] = o;
    } else {
        __shared__ float tmp[4][64];
        tmp[wid][lane] = o;
        __syncthreads();
        if (wid == 0) {
            float om = 0.25f * (tmp[0][lane] + tmp[1][lane] + tmp[2][lane] + tmp[3][lane])
                       + bias[lane];
            out[n * 64 + lane] = om;
        }
    }
}

// ---------------------------------------------------------------- mean pool accumulation (pool/cnt zeroed)
__global__ __launch_bounds__(256) void k_pool(const float* __restrict__ h,
                                              const int* __restrict__ batch,
                                              float* __restrict__ pool,
                                              float* __restrict__ cnt) {
    int idx = blockIdx.x * 256 + threadIdx.x;   // grid exactly NN*64
    int n = idx >> 6, c = idx & 63;
    if (n >= NN) return;
    int b = batch[n];
    atomicAdd(&pool[b * 64 + c], h[idx]);
    if (c == 0) atomicAdd(&cnt[b], 1.f);
}

// ---------------------------------------------------------------- MLP head (single block), FP32 out
__global__ __launch_bounds__(256) void k_mlp(const float* __restrict__ pool,
                                             const float* __restrict__ cnt,
                                             const float* __restrict__ M0W,
                                             const float* __restrict__ M0b,
                                             const float* __restrict__ M1W,
                                             const float* __restrict__ M1b,
                                             float* __restrict__ out) {
    __shared__ float g[64][64];
    __shared__ float t1[64][64];
    int tid = threadIdx.x;
    for (int idx = tid; idx < 4096; idx += 256) {
        int i = idx >> 6;
        g[i][idx & 63] = pool[idx] / fmaxf(cnt[i], 1.f);
    }
    __syncthreads();
    for (int idx = tid; idx < 4096; idx += 256) {
        int i = idx >> 6, j = idx & 63;
        float acc = M0b[j];
        for (int k = 0; k < 64; ++k) acc = fmaf(g[i][k], M0W[k * 64 + j], acc);
        t1[i][j] = fmaxf(acc, 0.f);
    }
    __syncthreads();
    for (int idx = tid; idx < NG * DOUT; idx += 256) {
        int i = idx / DOUT, j = idx % DOUT;
        float acc = M1b[j];
        for (int k = 0; k < 64; ++k) acc = fmaf(t1[i][k], M1W[k * DOUT + j], acc);
        out[idx] = acc;    // fp32 output (reference output dtype)
    }
}

extern "C" void kernel_launch(void* const* d_in, const int* in_sizes, int n_in,
                              void* d_out, int out_size, void* d_ws, size_t ws_size,
                              hipStream_t stream) {
    const float* x   = (const float*)d_in[0];
    const int*   ei  = (const int*)d_in[1];
    const int*   bat = (const int*)d_in[2];
    const float* A_W = (const float*)d_in[3];
    const float* A_b = (const float*)d_in[4];
    const float* W0  = (const float*)d_in[5];
    const float* as0 = (const float*)d_in[6];
    const float* ad0 = (const float*)d_in[7];
    const float* b0  = (const float*)d_in[8];
    const float* W1  = (const float*)d_in[9];
    const float* as1 = (const float*)d_in[10];
    const float* ad1 = (const float*)d_in[11];
    const float* b1  = (const float*)d_in[12];
    const float* W2  = (const float*)d_in[13];
    const float* as2 = (const float*)d_in[14];
    const float* ad2 = (const float*)d_in[15];
    const float* b2  = (const float*)d_in[16];
    const float* M0W = (const float*)d_in[17];
    const float* M0b = (const float*)d_in[18];
    const float* M1W = (const float*)d_in[19];
    const float* M1b = (const float*)d_in[20];

    char* ws = (char*)d_ws;
    float* hA      = (float*)(ws);                 // 51.2 MB f32 [NN,256] (h; layer2 out uses first 12.8MB)
    float* hB      = (float*)(ws + 51200000);      // 51.2 MB f32 [NN,256] h_lin
    float* ss      = (float*)(ws + 102400000);     // [NN,4]
    float* sd      = (float*)(ws + 103200000);     // [NN,4]
    int*   row_ptr = (int*)  (ws + 104000000);     // [NN+1]
    int*   cursor  = (int*)  (ws + 104200064);     // [NN] (also degree)
    int*   col_idx = (int*)  (ws + 104400128);     // [NEP]
    float* pool    = (float*)(ws + 107800128);     // [NG,64]
    float* cnt     = (float*)(ws + 107816512);     // [NG]

    const int EB = (NEP + 255) / 256;     // 3321

    // input projection
    k_lin0f<<<(NN * 64) / 256, 256, 0, stream>>>(x, A_W, A_b, hA);

    // CSR build (once per call; same edges for all 3 layers)
    hipMemsetAsync(cursor, 0, NN * sizeof(int), stream);
    k_degree<<<EB, 256, 0, stream>>>(ei, cursor);
    k_scan<<<1, 256, 0, stream>>>(cursor, row_ptr);
    hipMemsetAsync(cursor, 0, NN * sizeof(int), stream);
    k_scatter<<<EB, 256, 0, stream>>>(ei, row_ptr, cursor, col_idx);

    dim3 ggrid(782, 4);
    // layer 0 (K=64)
    k_gemm<64><<<ggrid, 256, 0, stream>>>(hA, W0, hB);
    k_scores<<<12500, 256, 0, stream>>>(hB, as0, ad0, ss, sd);
    k_agg<0><<<NN, 256, 0, stream>>>(hB, ss, sd, row_ptr, col_idx, b0, hA);
    // layer 1 (K=256)
    k_gemm<256><<<ggrid, 256, 0, stream>>>(hA, W1, hB);
    k_scores<<<12500, 256, 0, stream>>>(hB, as1, ad1, ss, sd);
    k_agg<0><<<NN, 256, 0, stream>>>(hB, ss, sd, row_ptr, col_idx, b1, hA);
    // layer 2 (K=256, head-mean -> [NN,64] into hA)
    k_gemm<256><<<ggrid, 256, 0, stream>>>(hA, W2, hB);
    k_scores<<<12500, 256, 0, stream>>>(hB, as2, ad2, ss, sd);
    k_agg<1><<<NN, 256, 0, stream>>>(hB, ss, sd, row_ptr, col_idx, b2, hA);

    // pooling + MLP head
    hipMemsetAsync(pool, 0, (NG * 64 + NG) * sizeof(float), stream);   // pool + cnt contiguous
    k_pool<<<(NN * 64) / 256, 256, 0, stream>>>(hA, bat, pool, cnt);
    k_mlp<<<1, 256, 0, stream>>>(pool, cnt, M0W, M0b, M1W, M1b, (float*)d_out);
}

// Round 9
// 1244.026 us; speedup vs baseline: 3.7342x; 1.2321x over previous
//
#include <hip/hip_runtime.h>
#include <hip/hip_bf16.h>

#define NN   50000
#define NE   800000
#define NEP  850000   // NE + NN self loops
#define NG   64
#define HH   256      // 4 heads * 64 ch
#define DOUT 10

// ---------------------------------------------------------------- h0 = x@A_W + A_b -> f32 [NN,64]
__global__ __launch_bounds__(256) void k_lin0f(const float* __restrict__ x,
                                               const float* __restrict__ W,
                                               const float* __restrict__ b,
                                               float* __restrict__ out) {
    int idx = blockIdx.x * 256 + threadIdx.x;   // grid exactly NN*64
    int n = idx >> 6, c = idx & 63;
    if (n >= NN) return;
    float acc = b[c];
    #pragma unroll
    for (int k = 0; k < 16; ++k) acc = fmaf(x[n * 16 + k], W[k * 64 + c], acc);
    out[idx] = acc;
}

// ---------------------------------------------------------------- degree histogram (deg passed zeroed)
__global__ __launch_bounds__(256) void k_degree(const int* __restrict__ ei, int* __restrict__ deg) {
    int e = blockIdx.x * 256 + threadIdx.x;
    if (e >= NEP) return;
    int dst = (e < NE) ? ei[NE + e] : (e - NE);
    atomicAdd(&deg[dst], 1);
}

// ---------------------------------------------------------------- exclusive scan, 1 block x 256 thr
__global__ __launch_bounds__(256) void k_scan(const int* __restrict__ deg, int* __restrict__ row_ptr) {
    __shared__ int psum[256];
    const int CH = 196;                 // 256*196 = 50176 >= NN
    int tid = threadIdx.x;
    int lo = tid * CH;
    int hi = lo + CH; if (hi > NN) hi = NN;
    int s = 0;
    for (int i = lo; i < hi; ++i) s += deg[i];
    psum[tid] = s;
    __syncthreads();
    if (tid == 0) {
        int run = 0;
        for (int i = 0; i < 256; ++i) { int v = psum[i]; psum[i] = run; run += v; }
    }
    __syncthreads();
    int run = psum[tid];
    for (int i = lo; i < hi; ++i) { row_ptr[i] = run; run += deg[i]; }
    if (tid == 255) row_ptr[NN] = run;
}

// ---------------------------------------------------------------- CSR scatter (cursor passed zeroed)
__global__ __launch_bounds__(256) void k_scatter(const int* __restrict__ ei,
                                                 const int* __restrict__ row_ptr,
                                                 int* __restrict__ cursor,
                                                 int* __restrict__ col_idx) {
    int e = blockIdx.x * 256 + threadIdx.x;
    if (e >= NEP) return;
    int src, dst;
    if (e < NE) { src = ei[e]; dst = ei[NE + e]; }
    else        { src = e - NE; dst = e - NE; }
    int pos = atomicAdd(&cursor[dst], 1);
    col_idx[row_ptr[dst] + pos] = src;
}

// ---------------------------------------------------------------- C[NN,256] = A[NN,K] @ B[K,256], tiled
template <int K>
__global__ __launch_bounds__(256) void k_gemm(const float* __restrict__ A,
                                              const float* __restrict__ B,
                                              float* __restrict__ C) {
    __shared__ float As[16][64];
    __shared__ float Bs[16][64];
    int tid = threadIdx.x;
    int tx = tid & 15, ty = tid >> 4;
    int m0 = blockIdx.x * 64, n0 = blockIdx.y * 64;
    float acc[4][4] = {};
    for (int k0 = 0; k0 < K; k0 += 16) {
        {   // stage A 64x16, transposed into As[k][m]
            int r = tid >> 2;
            int c = (tid & 3) << 2;
            int gr = m0 + r; if (gr >= NN) gr = NN - 1;
            const float4 a4 = *reinterpret_cast<const float4*>(&A[gr * K + k0 + c]);
            As[c + 0][r] = a4.x; As[c + 1][r] = a4.y; As[c + 2][r] = a4.z; As[c + 3][r] = a4.w;
        }
        {   // stage B 16x64
            int r = tid >> 4;
            int c = (tid & 15) << 2;
            *reinterpret_cast<float4*>(&Bs[r][c]) =
                *reinterpret_cast<const float4*>(&B[(k0 + r) * HH + n0 + c]);
        }
        __syncthreads();
        #pragma unroll
        for (int kk = 0; kk < 16; ++kk) {
            float4 a4 = *reinterpret_cast<const float4*>(&As[kk][ty << 2]);
            float4 b4 = *reinterpret_cast<const float4*>(&Bs[kk][tx << 2]);
            float av[4] = {a4.x, a4.y, a4.z, a4.w};
            float bv[4] = {b4.x, b4.y, b4.z, b4.w};
            #pragma unroll
            for (int i = 0; i < 4; ++i)
                #pragma unroll
                for (int j = 0; j < 4; ++j)
                    acc[i][j] = fmaf(av[i], bv[j], acc[i][j]);
        }
        __syncthreads();
    }
    #pragma unroll
    for (int i = 0; i < 4; ++i) {
        int m = m0 + (ty << 2) + i;
        if (m < NN) {
            float4 o = make_float4(acc[i][0], acc[i][1], acc[i][2], acc[i][3]);
            *reinterpret_cast<float4*>(&C[m * HH + n0 + (tx << 2)]) = o;
        }
    }
}

// ---------------------------------------------------------------- ss/sd[n][h] (1 wave/node, shuffle reduce)
__global__ __launch_bounds__(256) void k_scores(const float* __restrict__ hlin,
                                                const float* __restrict__ a_s,
                                                const float* __restrict__ a_d,
                                                float* __restrict__ ss,
                                                float* __restrict__ sd) {
    int wid = threadIdx.x >> 6, lane = threadIdx.x & 63;
    int n = blockIdx.x * 4 + wid;
    if (n >= NN) return;
    float accs[4], accd[4];
    #pragma unroll
    for (int j = 0; j < 4; ++j) {
        float hv = hlin[n * HH + (j << 6) + lane];
        accs[j] = hv * a_s[(j << 6) + lane];
        accd[j] = hv * a_d[(j << 6) + lane];
    }
    #pragma unroll
    for (int d = 1; d < 64; d <<= 1) {
        #pragma unroll
        for (int j = 0; j < 4; ++j) {
            accs[j] += __shfl_xor(accs[j], d, 64);
            accd[j] += __shfl_xor(accd[j], d, 64);
        }
    }
    if (lane == 0) {
        #pragma unroll
        for (int j = 0; j < 4; ++j) { ss[n * 4 + j] = accs[j]; sd[n * 4 + j] = accd[j]; }
    }
}

// ---------------------------------------------------------------- per-node online-softmax aggregation (no atomics)
// MODE 0: concat + bias + elu -> [NN,256];  MODE 1: head-mean + bias -> [NN,64]
template <int MODE>
__global__ __launch_bounds__(256) void k_agg(const float* __restrict__ hlin,
                                             const float* __restrict__ ss,
                                             const float* __restrict__ sd,
                                             const int* __restrict__ row_ptr,
                                             const int* __restrict__ col_idx,
                                             const float* __restrict__ bias,
                                             float* __restrict__ out) {
    int n = blockIdx.x;
    int wid = threadIdx.x >> 6, lane = threadIdx.x & 63;  // wave = head, lane = channel
    int rs = row_ptr[n], re = row_ptr[n + 1];
    float sdn = sd[n * 4 + wid];
    // first edge (self-loop guarantees re > rs)
    int sn = col_idx[rs];
    float sc = ss[sn * 4 + wid] + sdn;
    sc = (sc > 0.f) ? sc : 0.2f * sc;                     // leaky_relu 0.2
    float m = sc, s = 1.f;
    float acc = hlin[sn * HH + (wid << 6) + lane];
    for (int e = rs + 1; e < re; ++e) {
        sn = col_idx[e];
        sc = ss[sn * 4 + wid] + sdn;
        sc = (sc > 0.f) ? sc : 0.2f * sc;
        float hv = hlin[sn * HH + (wid << 6) + lane];
        float mn = fmaxf(m, sc);
        float corr = __expf(m - mn);
        float p = __expf(sc - mn);
        s = s * corr + p;
        acc = acc * corr + p * hv;
        m = mn;
    }
    float o = acc / s;
    if (MODE == 0) {
        o += bias[(wid << 6) + lane];
        o = (o > 0.f) ? o : (__expf(o) - 1.f);            // elu
        out[n * HH + (wid << 6) + lane] = o;
    } else {
        __shared__ float tmp[4][64];
        tmp[wid][lane] = o;
        __syncthreads();
        if (wid == 0) {
            float om = 0.25f * (tmp[0][lane] + tmp[1][lane] + tmp[2][lane] + tmp[3][lane])
                       + bias[lane];
            out[n * 64 + lane] = om;
        }
    }
}

// ---------------------------------------------------------------- graph boundaries in sorted batch
__global__ void k_bounds(const int* __restrict__ batch, int* __restrict__ gs) {
    int g = threadIdx.x;                         // 1 block, 64 threads
    if (g < NG) {
        int lo = 0, hi = NN;
        while (lo < hi) { int mid = (lo + hi) >> 1; if (batch[mid] < g) lo = mid + 1; else hi = mid; }
        gs[g] = lo;                              // first index with batch >= g
    }
    if (g == 0) gs[NG] = NN;
}

// ---------------------------------------------------------------- mean pool, 1 block/graph, no atomics
__global__ __launch_bounds__(256) void k_poolG(const float* __restrict__ h,
                                               const int* __restrict__ gs,
                                               float* __restrict__ pool) {
    __shared__ float part[4][64];
    int g = blockIdx.x;
    int c = threadIdx.x & 63, r = threadIdx.x >> 6;
    int s = gs[g], e = gs[g + 1];
    float acc = 0.f;
    for (int n = s + r; n < e; n += 4) acc += h[n * 64 + c];
    part[r][c] = acc;
    __syncthreads();
    if (r == 0) {
        float v = part[0][c] + part[1][c] + part[2][c] + part[3][c];
        pool[g * 64 + c] = v / fmaxf((float)(e - s), 1.f);   // mean (0 if empty graph)
    }
}

// ---------------------------------------------------------------- MLP head (single block), FP32 out
__global__ __launch_bounds__(256) void k_mlp(const float* __restrict__ pool,
                                             const float* __restrict__ M0W,
                                             const float* __restrict__ M0b,
                                             const float* __restrict__ M1W,
                                             const float* __restrict__ M1b,
                                             float* __restrict__ out) {
    __shared__ float g[64][64];
    __shared__ float t1[64][64];
    int tid = threadIdx.x;
    for (int idx = tid; idx < 4096; idx += 256) {
        g[idx >> 6][idx & 63] = pool[idx];       // already averaged
    }
    __syncthreads();
    for (int idx = tid; idx < 4096; idx += 256) {
        int i = idx >> 6, j = idx & 63;
        float acc = M0b[j];
        for (int k = 0; k < 64; ++k) acc = fmaf(g[i][k], M0W[k * 64 + j], acc);
        t1[i][j] = fmaxf(acc, 0.f);
    }
    __syncthreads();
    for (int idx = tid; idx < NG * DOUT; idx += 256) {
        int i = idx / DOUT, j = idx % DOUT;
        float acc = M1b[j];
        for (int k = 0; k < 64; ++k) acc = fmaf(t1[i][k], M1W[k * DOUT + j], acc);
        out[idx] = acc;                          // fp32 output (reference output dtype)
    }
}

extern "C" void kernel_launch(void* const* d_in, const int* in_sizes, int n_in,
                              void* d_out, int out_size, void* d_ws, size_t ws_size,
                              hipStream_t stream) {
    const float* x   = (const float*)d_in[0];
    const int*   ei  = (const int*)d_in[1];
    const int*   bat = (const int*)d_in[2];
    const float* A_W = (const float*)d_in[3];
    const float* A_b = (const float*)d_in[4];
    const float* W0  = (const float*)d_in[5];
    const float* as0 = (const float*)d_in[6];
    const float* ad0 = (const float*)d_in[7];
    const float* b0  = (const float*)d_in[8];
    const float* W1  = (const float*)d_in[9];
    const float* as1 = (const float*)d_in[10];
    const float* ad1 = (const float*)d_in[11];
    const float* b1  = (const float*)d_in[12];
    const float* W2  = (const float*)d_in[13];
    const float* as2 = (const float*)d_in[14];
    const float* ad2 = (const float*)d_in[15];
    const float* b2  = (const float*)d_in[16];
    const float* M0W = (const float*)d_in[17];
    const float* M0b = (const float*)d_in[18];
    const float* M1W = (const float*)d_in[19];
    const float* M1b = (const float*)d_in[20];

    char* ws = (char*)d_ws;
    float* hA      = (float*)(ws);                 // 51.2 MB f32 [NN,256] (h; layer2 out uses first 12.8MB)
    float* hB      = (float*)(ws + 51200000);      // 51.2 MB f32 [NN,256] h_lin
    float* ss      = (float*)(ws + 102400000);     // [NN,4]
    float* sd      = (float*)(ws + 103200000);     // [NN,4]
    int*   row_ptr = (int*)  (ws + 104000000);     // [NN+1]
    int*   cursor  = (int*)  (ws + 104200064);     // [NN] (also degree)
    int*   col_idx = (int*)  (ws + 104400128);     // [NEP]
    float* pool    = (float*)(ws + 107800128);     // [NG,64]
    int*   gs      = (int*)  (ws + 107816512);     // [NG+1] graph boundaries

    const int EB = (NEP + 255) / 256;     // 3321

    // input projection
    k_lin0f<<<(NN * 64) / 256, 256, 0, stream>>>(x, A_W, A_b, hA);

    // CSR build (once per call; same edges for all 3 layers)
    hipMemsetAsync(cursor, 0, NN * sizeof(int), stream);
    k_degree<<<EB, 256, 0, stream>>>(ei, cursor);
    k_scan<<<1, 256, 0, stream>>>(cursor, row_ptr);
    hipMemsetAsync(cursor, 0, NN * sizeof(int), stream);
    k_scatter<<<EB, 256, 0, stream>>>(ei, row_ptr, cursor, col_idx);

    dim3 ggrid(782, 4);
    // layer 0 (K=64)
    k_gemm<64><<<ggrid, 256, 0, stream>>>(hA, W0, hB);
    k_scores<<<12500, 256, 0, stream>>>(hB, as0, ad0, ss, sd);
    k_agg<0><<<NN, 256, 0, stream>>>(hB, ss, sd, row_ptr, col_idx, b0, hA);
    // layer 1 (K=256)
    k_gemm<256><<<ggrid, 256, 0, stream>>>(hA, W1, hB);
    k_scores<<<12500, 256, 0, stream>>>(hB, as1, ad1, ss, sd);
    k_agg<0><<<NN, 256, 0, stream>>>(hB, ss, sd, row_ptr, col_idx, b1, hA);
    // layer 2 (K=256, head-mean -> [NN,64] into hA)
    k_gemm<256><<<ggrid, 256, 0, stream>>>(hA, W2, hB);
    k_scores<<<12500, 256, 0, stream>>>(hB, as2, ad2, ss, sd);
    k_agg<1><<<NN, 256, 0, stream>>>(hB, ss, sd, row_ptr, col_idx, b2, hA);

    // pooling (sorted batch -> segment reduce, no atomics) + MLP head
    k_bounds<<<1, 64, 0, stream>>>(bat, gs);
    k_poolG<<<NG, 256, 0, stream>>>(hA, gs, pool);
    k_mlp<<<1, 256, 0, stream>>>(pool, M0W, M0b, M1W, M1b, (float*)d_out);
}

// Round 10
// 969.815 us; speedup vs baseline: 4.7901x; 1.2827x over previous
//
#include <hip/hip_runtime.h>
#include <hip/hip_bf16.h>

#define NN   50000
#define NE   800000
#define NEP  850000   // NE + NN self loops
#define NG   64
#define HH   256      // 4 heads * 64 ch
#define DOUT 10

__device__ inline float bf2f(ushort u) {
    union { unsigned int i; float f; } v; v.i = ((unsigned int)u) << 16; return v.f;
}
__device__ inline ushort f2bf(float f) {   // round-to-nearest-even (finite)
    union { float f; unsigned int i; } v; v.f = f;
    unsigned int x = v.i;
    return (ushort)((x + 0x7FFFu + ((x >> 16) & 1u)) >> 16);
}

// ---------------------------------------------------------------- h0 = x@A_W + A_b -> f32 [NN,64]
__global__ __launch_bounds__(256) void k_lin0f(const float* __restrict__ x,
                                               const float* __restrict__ W,
                                               const float* __restrict__ b,
                                               float* __restrict__ out) {
    int idx = blockIdx.x * 256 + threadIdx.x;   // grid exactly NN*64
    int n = idx >> 6, c = idx & 63;
    if (n >= NN) return;
    float acc = b[c];
    #pragma unroll
    for (int k = 0; k < 16; ++k) acc = fmaf(x[n * 16 + k], W[k * 64 + c], acc);
    out[idx] = acc;
}

// ---------------------------------------------------------------- degree histogram (deg passed zeroed)
__global__ __launch_bounds__(256) void k_degree(const int* __restrict__ ei, int* __restrict__ deg) {
    int e = blockIdx.x * 256 + threadIdx.x;
    if (e >= NEP) return;
    int dst = (e < NE) ? ei[NE + e] : (e - NE);
    atomicAdd(&deg[dst], 1);
}

// ---------------------------------------------------------------- exclusive scan, 1 block x 256 thr
__global__ __launch_bounds__(256) void k_scan(const int* __restrict__ deg, int* __restrict__ row_ptr) {
    __shared__ int psum[256];
    const int CH = 196;                 // 256*196 = 50176 >= NN
    int tid = threadIdx.x;
    int lo = tid * CH;
    int hi = lo + CH; if (hi > NN) hi = NN;
    int s = 0;
    for (int i = lo; i < hi; ++i) s += deg[i];
    psum[tid] = s;
    __syncthreads();
    if (tid == 0) {
        int run = 0;
        for (int i = 0; i < 256; ++i) { int v = psum[i]; psum[i] = run; run += v; }
    }
    __syncthreads();
    int run = psum[tid];
    for (int i = lo; i < hi; ++i) { row_ptr[i] = run; run += deg[i]; }
    if (tid == 255) row_ptr[NN] = run;
}

// ---------------------------------------------------------------- CSR scatter (cursor passed zeroed)
__global__ __launch_bounds__(256) void k_scatter(const int* __restrict__ ei,
                                                 const int* __restrict__ row_ptr,
                                                 int* __restrict__ cursor,
                                                 int* __restrict__ col_idx) {
    int e = blockIdx.x * 256 + threadIdx.x;
    if (e >= NEP) return;
    int src, dst;
    if (e < NE) { src = ei[e]; dst = ei[NE + e]; }
    else        { src = e - NE; dst = e - NE; }
    int pos = atomicAdd(&cursor[dst], 1);
    col_idx[row_ptr[dst] + pos] = src;
}

// ---------------------------------------------------------------- C[NN,256](bf16) = A[NN,K](f32) @ B[K,256](f32)
template <int K>
__global__ __launch_bounds__(256) void k_gemm(const float* __restrict__ A,
                                              const float* __restrict__ B,
                                              ushort* __restrict__ C) {
    __shared__ float As[16][64];
    __shared__ float Bs[16][64];
    int tid = threadIdx.x;
    int tx = tid & 15, ty = tid >> 4;
    int m0 = blockIdx.x * 64, n0 = blockIdx.y * 64;
    float acc[4][4] = {};
    for (int k0 = 0; k0 < K; k0 += 16) {
        {   // stage A 64x16, transposed into As[k][m]
            int r = tid >> 2;
            int c = (tid & 3) << 2;
            int gr = m0 + r; if (gr >= NN) gr = NN - 1;
            const float4 a4 = *reinterpret_cast<const float4*>(&A[gr * K + k0 + c]);
            As[c + 0][r] = a4.x; As[c + 1][r] = a4.y; As[c + 2][r] = a4.z; As[c + 3][r] = a4.w;
        }
        {   // stage B 16x64
            int r = tid >> 4;
            int c = (tid & 15) << 2;
            *reinterpret_cast<float4*>(&Bs[r][c]) =
                *reinterpret_cast<const float4*>(&B[(k0 + r) * HH + n0 + c]);
        }
        __syncthreads();
        #pragma unroll
        for (int kk = 0; kk < 16; ++kk) {
            float4 a4 = *reinterpret_cast<const float4*>(&As[kk][ty << 2]);
            float4 b4 = *reinterpret_cast<const float4*>(&Bs[kk][tx << 2]);
            float av[4] = {a4.x, a4.y, a4.z, a4.w};
            float bv[4] = {b4.x, b4.y, b4.z, b4.w};
            #pragma unroll
            for (int i = 0; i < 4; ++i)
                #pragma unroll
                for (int j = 0; j < 4; ++j)
                    acc[i][j] = fmaf(av[i], bv[j], acc[i][j]);
        }
        __syncthreads();
    }
    #pragma unroll
    for (int i = 0; i < 4; ++i) {
        int m = m0 + (ty << 2) + i;
        if (m < NN) {
            ushort4 o;
            o.x = f2bf(acc[i][0]); o.y = f2bf(acc[i][1]);
            o.z = f2bf(acc[i][2]); o.w = f2bf(acc[i][3]);
            *reinterpret_cast<ushort4*>(&C[m * HH + n0 + (tx << 2)]) = o;
        }
    }
}

// ---------------------------------------------------------------- ss/sd[n][h] from bf16 h_lin (1 wave/node)
__global__ __launch_bounds__(256) void k_scores(const ushort* __restrict__ hlin,
                                                const float* __restrict__ a_s,
                                                const float* __restrict__ a_d,
                                                float* __restrict__ ss,
                                                float* __restrict__ sd) {
    int wid = threadIdx.x >> 6, lane = threadIdx.x & 63;
    int n = blockIdx.x * 4 + wid;
    if (n >= NN) return;
    float accs[4], accd[4];
    #pragma unroll
    for (int j = 0; j < 4; ++j) {
        float hv = bf2f(hlin[n * HH + (j << 6) + lane]);
        accs[j] = hv * a_s[(j << 6) + lane];
        accd[j] = hv * a_d[(j << 6) + lane];
    }
    #pragma unroll
    for (int d = 1; d < 64; d <<= 1) {
        #pragma unroll
        for (int j = 0; j < 4; ++j) {
            accs[j] += __shfl_xor(accs[j], d, 64);
            accd[j] += __shfl_xor(accd[j], d, 64);
        }
    }
    if (lane == 0) {
        #pragma unroll
        for (int j = 0; j < 4; ++j) { ss[n * 4 + j] = accs[j]; sd[n * 4 + j] = accd[j]; }
    }
}

// ---------------------------------------------------------------- online-softmax aggregation, 1 WAVE/node
// lane l: head = l>>4, channels c4..c4+3 (c4 = (l&15)*4); 8B ushort4 gather -> 512B/wave/edge
// MODE 0: concat + bias + elu -> f32 [NN,256];  MODE 1: head-mean + bias -> f32 [NN,64]
template <int MODE>
__global__ __launch_bounds__(256) void k_agg(const ushort* __restrict__ hlin,
                                             const float* __restrict__ ss,
                                             const float* __restrict__ sd,
                                             const int* __restrict__ row_ptr,
                                             const int* __restrict__ col_idx,
                                             const float* __restrict__ bias,
                                             float* __restrict__ out) {
    int wid = threadIdx.x >> 6, lane = threadIdx.x & 63;
    int n = blockIdx.x * 4 + wid;                     // NN = 12500*4 exactly
    int h = lane >> 4, c4 = (lane & 15) << 2;
    int rs = row_ptr[n], re = row_ptr[n + 1];
    float sdn = sd[n * 4 + h];
    // first edge (self-loop guarantees re > rs)
    int sn = col_idx[rs];
    float sc = ss[sn * 4 + h] + sdn;
    sc = (sc > 0.f) ? sc : 0.2f * sc;                 // leaky_relu 0.2
    float m = sc, s = 1.f;
    ushort4 hv = *reinterpret_cast<const ushort4*>(&hlin[sn * HH + (h << 6) + c4]);
    float a0 = bf2f(hv.x), a1 = bf2f(hv.y), a2 = bf2f(hv.z), a3 = bf2f(hv.w);
    for (int e = rs + 1; e < re; ++e) {
        sn = col_idx[e];
        sc = ss[sn * 4 + h] + sdn;
        sc = (sc > 0.f) ? sc : 0.2f * sc;
        hv = *reinterpret_cast<const ushort4*>(&hlin[sn * HH + (h << 6) + c4]);
        float mn = fmaxf(m, sc);
        float corr = __expf(m - mn);
        float p = __expf(sc - mn);
        s = s * corr + p;
        a0 = a0 * corr + p * bf2f(hv.x);
        a1 = a1 * corr + p * bf2f(hv.y);
        a2 = a2 * corr + p * bf2f(hv.z);
        a3 = a3 * corr + p * bf2f(hv.w);
        m = mn;
    }
    float inv = 1.f / s;
    float o0 = a0 * inv, o1 = a1 * inv, o2 = a2 * inv, o3 = a3 * inv;
    if (MODE == 0) {
        o0 += bias[(h << 6) + c4 + 0];
        o1 += bias[(h << 6) + c4 + 1];
        o2 += bias[(h << 6) + c4 + 2];
        o3 += bias[(h << 6) + c4 + 3];
        o0 = (o0 > 0.f) ? o0 : (__expf(o0) - 1.f);    // elu
        o1 = (o1 > 0.f) ? o1 : (__expf(o1) - 1.f);
        o2 = (o2 > 0.f) ? o2 : (__expf(o2) - 1.f);
        o3 = (o3 > 0.f) ? o3 : (__expf(o3) - 1.f);
        *reinterpret_cast<float4*>(&out[n * HH + (h << 6) + c4]) =
            make_float4(o0, o1, o2, o3);
    } else {
        // mean over heads: lanes l, l^16, l^32, l^48 hold same channel group
        o0 += __shfl_xor(o0, 16, 64); o0 += __shfl_xor(o0, 32, 64);
        o1 += __shfl_xor(o1, 16, 64); o1 += __shfl_xor(o1, 32, 64);
        o2 += __shfl_xor(o2, 16, 64); o2 += __shfl_xor(o2, 32, 64);
        o3 += __shfl_xor(o3, 16, 64); o3 += __shfl_xor(o3, 32, 64);
        if (h == 0) {
            float4 o = make_float4(0.25f * o0 + bias[c4 + 0],
                                   0.25f * o1 + bias[c4 + 1],
                                   0.25f * o2 + bias[c4 + 2],
                                   0.25f * o3 + bias[c4 + 3]);
            *reinterpret_cast<float4*>(&out[n * 64 + c4]) = o;
        }
    }
}

// ---------------------------------------------------------------- graph boundaries in sorted batch
__global__ void k_bounds(const int* __restrict__ batch, int* __restrict__ gs) {
    int g = threadIdx.x;                         // 1 block, 64 threads
    if (g < NG) {
        int lo = 0, hi = NN;
        while (lo < hi) { int mid = (lo + hi) >> 1; if (batch[mid] < g) lo = mid + 1; else hi = mid; }
        gs[g] = lo;
    }
    if (g == 0) gs[NG] = NN;
}

// ---------------------------------------------------------------- mean pool, 1 block/graph, no atomics
__global__ __launch_bounds__(256) void k_poolG(const float* __restrict__ h,
                                               const int* __restrict__ gs,
                                               float* __restrict__ pool) {
    __shared__ float part[4][64];
    int g = blockIdx.x;
    int c = threadIdx.x & 63, r = threadIdx.x >> 6;
    int s = gs[g], e = gs[g + 1];
    float acc = 0.f;
    for (int n = s + r; n < e; n += 4) acc += h[n * 64 + c];
    part[r][c] = acc;
    __syncthreads();
    if (r == 0) {
        float v = part[0][c] + part[1][c] + part[2][c] + part[3][c];
        pool[g * 64 + c] = v / fmaxf((float)(e - s), 1.f);
    }
}

// ---------------------------------------------------------------- MLP head (single block), FP32 out
__global__ __launch_bounds__(256) void k_mlp(const float* __restrict__ pool,
                                             const float* __restrict__ M0W,
                                             const float* __restrict__ M0b,
                                             const float* __restrict__ M1W,
                                             const float* __restrict__ M1b,
                                             float* __restrict__ out) {
    __shared__ float g[64][64];
    __shared__ float t1[64][64];
    int tid = threadIdx.x;
    for (int idx = tid; idx < 4096; idx += 256) {
        g[idx >> 6][idx & 63] = pool[idx];       // already averaged
    }
    __syncthreads();
    for (int idx = tid; idx < 4096; idx += 256) {
        int i = idx >> 6, j = idx & 63;
        float acc = M0b[j];
        for (int k = 0; k < 64; ++k) acc = fmaf(g[i][k], M0W[k * 64 + j], acc);
        t1[i][j] = fmaxf(acc, 0.f);
    }
    __syncthreads();
    for (int idx = tid; idx < NG * DOUT; idx += 256) {
        int i = idx / DOUT, j = idx % DOUT;
        float acc = M1b[j];
        for (int k = 0; k < 64; ++k) acc = fmaf(t1[i][k], M1W[k * DOUT + j], acc);
        out[idx] = acc;                          // fp32 output (reference output dtype)
    }
}

extern "C" void kernel_launch(void* const* d_in, const int* in_sizes, int n_in,
                              void* d_out, int out_size, void* d_ws, size_t ws_size,
                              hipStream_t stream) {
    const float* x   = (const float*)d_in[0];
    const int*   ei  = (const int*)d_in[1];
    const int*   bat = (const int*)d_in[2];
    const float* A_W = (const float*)d_in[3];
    const float* A_b = (const float*)d_in[4];
    const float* W0  = (const float*)d_in[5];
    const float* as0 = (const float*)d_in[6];
    const float* ad0 = (const float*)d_in[7];
    const float* b0  = (const float*)d_in[8];
    const float* W1  = (const float*)d_in[9];
    const float* as1 = (const float*)d_in[10];
    const float* ad1 = (const float*)d_in[11];
    const float* b1  = (const float*)d_in[12];
    const float* W2  = (const float*)d_in[13];
    const float* as2 = (const float*)d_in[14];
    const float* ad2 = (const float*)d_in[15];
    const float* b2  = (const float*)d_in[16];
    const float* M0W = (const float*)d_in[17];
    const float* M0b = (const float*)d_in[18];
    const float* M1W = (const float*)d_in[19];
    const float* M1b = (const float*)d_in[20];

    char* ws = (char*)d_ws;
    float*  hA      = (float*) (ws);                 // 51.2 MB f32 [NN,256] (agg out / gemm A)
    ushort* hB      = (ushort*)(ws + 51200000);      // 25.6 MB bf16 [NN,256] h_lin (gather source)
    float*  ss      = (float*) (ws + 102400000);     // [NN,4]
    float*  sd      = (float*) (ws + 103200000);     // [NN,4]
    int*    row_ptr = (int*)   (ws + 104000000);     // [NN+1]
    int*    cursor  = (int*)   (ws + 104200064);     // [NN] (also degree)
    int*    col_idx = (int*)   (ws + 104400128);     // [NEP]
    float*  pool    = (float*) (ws + 107800128);     // [NG,64]
    int*    gs      = (int*)   (ws + 107816512);     // [NG+1]

    const int EB = (NEP + 255) / 256;     // 3321

    // input projection
    k_lin0f<<<(NN * 64) / 256, 256, 0, stream>>>(x, A_W, A_b, hA);

    // CSR build (once per call)
    hipMemsetAsync(cursor, 0, NN * sizeof(int), stream);
    k_degree<<<EB, 256, 0, stream>>>(ei, cursor);
    k_scan<<<1, 256, 0, stream>>>(cursor, row_ptr);
    hipMemsetAsync(cursor, 0, NN * sizeof(int), stream);
    k_scatter<<<EB, 256, 0, stream>>>(ei, row_ptr, cursor, col_idx);

    dim3 ggrid(782, 4);
    // layer 0 (K=64)
    k_gemm<64><<<ggrid, 256, 0, stream>>>(hA, W0, hB);
    k_scores<<<12500, 256, 0, stream>>>(hB, as0, ad0, ss, sd);
    k_agg<0><<<12500, 256, 0, stream>>>(hB, ss, sd, row_ptr, col_idx, b0, hA);
    // layer 1 (K=256)
    k_gemm<256><<<ggrid, 256, 0, stream>>>(hA, W1, hB);
    k_scores<<<12500, 256, 0, stream>>>(hB, as1, ad1, ss, sd);
    k_agg<0><<<12500, 256, 0, stream>>>(hB, ss, sd, row_ptr, col_idx, b1, hA);
    // layer 2 (K=256, head-mean -> [NN,64] into hA)
    k_gemm<256><<<ggrid, 256, 0, stream>>>(hA, W2, hB);
    k_scores<<<12500, 256, 0, stream>>>(hB, as2, ad2, ss, sd);
    k_agg<1><<<12500, 256, 0, stream>>>(hB, ss, sd, row_ptr, col_idx, b2, hA);

    // pooling + MLP head
    k_bounds<<<1, 64, 0, stream>>>(bat, gs);
    k_poolG<<<NG, 256, 0, stream>>>(hA, gs, pool);
    k_mlp<<<1, 256, 0, stream>>>(pool, M0W, M0b, M1W, M1b, (float*)d_out);
}

// Round 11
// 807.334 us; speedup vs baseline: 5.7541x; 1.2013x over previous
//
#include <hip/hip_runtime.h>
#include <hip/hip_bf16.h>

#define NN   50000
#define NE   800000
#define NEP  850000   // NE + NN self loops
#define NG   64
#define HH   256      // 4 heads * 64 ch
#define DOUT 10

__device__ inline float bf2f(ushort u) {
    union { unsigned int i; float f; } v; v.i = ((unsigned int)u) << 16; return v.f;
}
__device__ inline ushort f2bf(float f) {   // round-to-nearest-even (finite)
    union { float f; unsigned int i; } v; v.f = f;
    unsigned int x = v.i;
    return (ushort)((x + 0x7FFFu + ((x >> 16) & 1u)) >> 16);
}

// ---------------------------------------------------------------- h0 = x@A_W + A_b -> f32 [NN,64]
__global__ __launch_bounds__(256) void k_lin0f(const float* __restrict__ x,
                                               const float* __restrict__ W,
                                               const float* __restrict__ b,
                                               float* __restrict__ out) {
    int idx = blockIdx.x * 256 + threadIdx.x;   // grid exactly NN*64
    int n = idx >> 6, c = idx & 63;
    if (n >= NN) return;
    float acc = b[c];
    #pragma unroll
    for (int k = 0; k < 16; ++k) acc = fmaf(x[n * 16 + k], W[k * 64 + c], acc);
    out[idx] = acc;
}

// ---------------------------------------------------------------- degree histogram (deg passed zeroed)
__global__ __launch_bounds__(256) void k_degree(const int* __restrict__ ei, int* __restrict__ deg) {
    int e = blockIdx.x * 256 + threadIdx.x;
    if (e >= NEP) return;
    int dst = (e < NE) ? ei[NE + e] : (e - NE);
    atomicAdd(&deg[dst], 1);
}

// ---------------------------------------------------------------- exclusive scan, 1 block x 256 thr
__global__ __launch_bounds__(256) void k_scan(const int* __restrict__ deg, int* __restrict__ row_ptr) {
    __shared__ int psum[256];
    const int CH = 196;                 // 256*196 = 50176 >= NN
    int tid = threadIdx.x;
    int lo = tid * CH;
    int hi = lo + CH; if (hi > NN) hi = NN;
    int s = 0;
    for (int i = lo; i < hi; ++i) s += deg[i];
    psum[tid] = s;
    __syncthreads();
    if (tid == 0) {
        int run = 0;
        for (int i = 0; i < 256; ++i) { int v = psum[i]; psum[i] = run; run += v; }
    }
    __syncthreads();
    int run = psum[tid];
    for (int i = lo; i < hi; ++i) { row_ptr[i] = run; run += deg[i]; }
    if (tid == 255) row_ptr[NN] = run;
}

// ---------------------------------------------------------------- CSR scatter (cursor passed zeroed)
__global__ __launch_bounds__(256) void k_scatter(const int* __restrict__ ei,
                                                 const int* __restrict__ row_ptr,
                                                 int* __restrict__ cursor,
                                                 int* __restrict__ col_idx) {
    int e = blockIdx.x * 256 + threadIdx.x;
    if (e >= NEP) return;
    int src, dst;
    if (e < NE) { src = ei[e]; dst = ei[NE + e]; }
    else        { src = e - NE; dst = e - NE; }
    int pos = atomicAdd(&cursor[dst], 1);
    col_idx[row_ptr[dst] + pos] = src;
}

// ---------------------------------------------------------------- C[NN,256](bf16) = A[NN,K](f32) @ B[K,256](f32)
// Fused epilogue: ss/sd[n][head] = dot(C_row_head, a_src/a_dst) from fp32 acc
// (block's 64-col tile == exactly one head since n0 = blockIdx.y*64)
template <int K>
__global__ __launch_bounds__(256) void k_gemm(const float* __restrict__ A,
                                              const float* __restrict__ B,
                                              ushort* __restrict__ C,
                                              const float* __restrict__ a_s,
                                              const float* __restrict__ a_d,
                                              float* __restrict__ ss,
                                              float* __restrict__ sd) {
    __shared__ float As[16][64];
    __shared__ float Bs[16][64];
    int tid = threadIdx.x;
    int tx = tid & 15, ty = tid >> 4;
    int m0 = blockIdx.x * 64, n0 = blockIdx.y * 64;
    float acc[4][4] = {};
    for (int k0 = 0; k0 < K; k0 += 16) {
        {   // stage A 64x16, transposed into As[k][m]
            int r = tid >> 2;
            int c = (tid & 3) << 2;
            int gr = m0 + r; if (gr >= NN) gr = NN - 1;
            const float4 a4 = *reinterpret_cast<const float4*>(&A[gr * K + k0 + c]);
            As[c + 0][r] = a4.x; As[c + 1][r] = a4.y; As[c + 2][r] = a4.z; As[c + 3][r] = a4.w;
        }
        {   // stage B 16x64
            int r = tid >> 4;
            int c = (tid & 15) << 2;
            *reinterpret_cast<float4*>(&Bs[r][c]) =
                *reinterpret_cast<const float4*>(&B[(k0 + r) * HH + n0 + c]);
        }
        __syncthreads();
        #pragma unroll
        for (int kk = 0; kk < 16; ++kk) {
            float4 a4 = *reinterpret_cast<const float4*>(&As[kk][ty << 2]);
            float4 b4 = *reinterpret_cast<const float4*>(&Bs[kk][tx << 2]);
            float av[4] = {a4.x, a4.y, a4.z, a4.w};
            float bv[4] = {b4.x, b4.y, b4.z, b4.w};
            #pragma unroll
            for (int i = 0; i < 4; ++i)
                #pragma unroll
                for (int j = 0; j < 4; ++j)
                    acc[i][j] = fmaf(av[i], bv[j], acc[i][j]);
        }
        __syncthreads();
    }
    #pragma unroll
    for (int i = 0; i < 4; ++i) {
        int m = m0 + (ty << 2) + i;
        if (m < NN) {
            ushort4 o;
            o.x = f2bf(acc[i][0]); o.y = f2bf(acc[i][1]);
            o.z = f2bf(acc[i][2]); o.w = f2bf(acc[i][3]);
            *reinterpret_cast<ushort4*>(&C[m * HH + n0 + (tx << 2)]) = o;
        }
    }
    // fused score epilogue
    int head = blockIdx.y;
    #pragma unroll
    for (int i = 0; i < 4; ++i) {
        float ps = 0.f, pd = 0.f;
        #pragma unroll
        for (int j = 0; j < 4; ++j) {
            int w = (tx << 2) + j;                      // within-head channel
            ps = fmaf(acc[i][j], a_s[(head << 6) + w], ps);
            pd = fmaf(acc[i][j], a_d[(head << 6) + w], pd);
        }
        #pragma unroll
        for (int d = 1; d < 16; d <<= 1) {              // reduce across tx (same-ty lanes)
            ps += __shfl_xor(ps, d, 64);
            pd += __shfl_xor(pd, d, 64);
        }
        int m = m0 + (ty << 2) + i;
        if (tx == 0 && m < NN) {
            ss[m * 4 + head] = ps;
            sd[m * 4 + head] = pd;
        }
    }
}

// ---------------------------------------------------------------- online-softmax aggregation, 1 WAVE/node
// lane l: head = l>>4, channels c4..c4+3; single-exp branchless update, unroll x2
// MODE 0: concat + bias + elu -> f32 [NN,256];  MODE 1: head-mean + bias -> f32 [NN,64]
template <int MODE>
__global__ __launch_bounds__(256) void k_agg(const ushort* __restrict__ hlin,
                                             const float* __restrict__ ss,
                                             const float* __restrict__ sd,
                                             const int* __restrict__ row_ptr,
                                             const int* __restrict__ col_idx,
                                             const float* __restrict__ bias,
                                             float* __restrict__ out) {
    int wid = threadIdx.x >> 6, lane = threadIdx.x & 63;
    int n = blockIdx.x * 4 + wid;                     // NN = 12500*4 exactly
    int h = lane >> 4, c4 = (lane & 15) << 2;
    int rs = row_ptr[n], re = row_ptr[n + 1];
    float sdn = sd[n * 4 + h];
    // first edge (self-loop guarantees re > rs)
    int sn = col_idx[rs];
    float sc = ss[sn * 4 + h] + sdn;
    sc = (sc > 0.f) ? sc : 0.2f * sc;                 // leaky_relu 0.2
    float m = sc, s = 1.f;
    ushort4 hv = *reinterpret_cast<const ushort4*>(&hlin[sn * HH + (h << 6) + c4]);
    float a0 = bf2f(hv.x), a1 = bf2f(hv.y), a2 = bf2f(hv.z), a3 = bf2f(hv.w);
    int e = rs + 1;
    for (; e + 1 < re; e += 2) {
        int sn0 = col_idx[e], sn1 = col_idx[e + 1];
        float t0 = ss[sn0 * 4 + h];
        float t1 = ss[sn1 * 4 + h];
        ushort4 u0 = *reinterpret_cast<const ushort4*>(&hlin[sn0 * HH + (h << 6) + c4]);
        ushort4 u1 = *reinterpret_cast<const ushort4*>(&hlin[sn1 * HH + (h << 6) + c4]);
        // edge 0: one exp, branchless select
        float s0 = t0 + sdn; s0 = (s0 > 0.f) ? s0 : 0.2f * s0;
        float mn = fmaxf(m, s0);
        float d  = __expf(fminf(m, s0) - mn);
        float cs = (s0 > m) ? d : 1.f;                // scale of old state
        float ph = (s0 > m) ? 1.f : d;                // weight of new term
        m = mn;
        s  = fmaf(s,  cs, ph);
        a0 = fmaf(a0, cs, ph * bf2f(u0.x));
        a1 = fmaf(a1, cs, ph * bf2f(u0.y));
        a2 = fmaf(a2, cs, ph * bf2f(u0.z));
        a3 = fmaf(a3, cs, ph * bf2f(u0.w));
        // edge 1
        float s1 = t1 + sdn; s1 = (s1 > 0.f) ? s1 : 0.2f * s1;
        mn = fmaxf(m, s1);
        d  = __expf(fminf(m, s1) - mn);
        cs = (s1 > m) ? d : 1.f;
        ph = (s1 > m) ? 1.f : d;
        m = mn;
        s  = fmaf(s,  cs, ph);
        a0 = fmaf(a0, cs, ph * bf2f(u1.x));
        a1 = fmaf(a1, cs, ph * bf2f(u1.y));
        a2 = fmaf(a2, cs, ph * bf2f(u1.z));
        a3 = fmaf(a3, cs, ph * bf2f(u1.w));
    }
    if (e < re) {                                     // tail edge
        int sn0 = col_idx[e];
        float t0 = ss[sn0 * 4 + h];
        ushort4 u0 = *reinterpret_cast<const ushort4*>(&hlin[sn0 * HH + (h << 6) + c4]);
        float s0 = t0 + sdn; s0 = (s0 > 0.f) ? s0 : 0.2f * s0;
        float mn = fmaxf(m, s0);
        float d  = __expf(fminf(m, s0) - mn);
        float cs = (s0 > m) ? d : 1.f;
        float ph = (s0 > m) ? 1.f : d;
        s  = fmaf(s,  cs, ph);
        a0 = fmaf(a0, cs, ph * bf2f(u0.x));
        a1 = fmaf(a1, cs, ph * bf2f(u0.y));
        a2 = fmaf(a2, cs, ph * bf2f(u0.z));
        a3 = fmaf(a3, cs, ph * bf2f(u0.w));
    }
    float inv = 1.f / s;
    float o0 = a0 * inv, o1 = a1 * inv, o2 = a2 * inv, o3 = a3 * inv;
    if (MODE == 0) {
        o0 += bias[(h << 6) + c4 + 0];
        o1 += bias[(h << 6) + c4 + 1];
        o2 += bias[(h << 6) + c4 + 2];
        o3 += bias[(h << 6) + c4 + 3];
        o0 = (o0 > 0.f) ? o0 : (__expf(o0) - 1.f);    // elu
        o1 = (o1 > 0.f) ? o1 : (__expf(o1) - 1.f);
        o2 = (o2 > 0.f) ? o2 : (__expf(o2) - 1.f);
        o3 = (o3 > 0.f) ? o3 : (__expf(o3) - 1.f);
        *reinterpret_cast<float4*>(&out[n * HH + (h << 6) + c4]) =
            make_float4(o0, o1, o2, o3);
    } else {
        // mean over heads: lanes l, l^16, l^32, l^48 hold same channel group
        o0 += __shfl_xor(o0, 16, 64); o0 += __shfl_xor(o0, 32, 64);
        o1 += __shfl_xor(o1, 16, 64); o1 += __shfl_xor(o1, 32, 64);
        o2 += __shfl_xor(o2, 16, 64); o2 += __shfl_xor(o2, 32, 64);
        o3 += __shfl_xor(o3, 16, 64); o3 += __shfl_xor(o3, 32, 64);
        if (h == 0) {
            float4 o = make_float4(0.25f * o0 + bias[c4 + 0],
                                   0.25f * o1 + bias[c4 + 1],
                                   0.25f * o2 + bias[c4 + 2],
                                   0.25f * o3 + bias[c4 + 3]);
            *reinterpret_cast<float4*>(&out[n * 64 + c4]) = o;
        }
    }
}

// ---------------------------------------------------------------- graph boundaries in sorted batch
__global__ void k_bounds(const int* __restrict__ batch, int* __restrict__ gs) {
    int g = threadIdx.x;                         // 1 block, 64 threads
    if (g < NG) {
        int lo = 0, hi = NN;
        while (lo < hi) { int mid = (lo + hi) >> 1; if (batch[mid] < g) lo = mid + 1; else hi = mid; }
        gs[g] = lo;
    }
    if (g == 0) gs[NG] = NN;
}

// ---------------------------------------------------------------- mean pool, 1 block/graph, no atomics
__global__ __launch_bounds__(256) void k_poolG(const float* __restrict__ h,
                                               const int* __restrict__ gs,
                                               float* __restrict__ pool) {
    __shared__ float part[4][64];
    int g = blockIdx.x;
    int c = threadIdx.x & 63, r = threadIdx.x >> 6;
    int s = gs[g], e = gs[g + 1];
    float acc = 0.f;
    for (int n = s + r; n < e; n += 4) acc += h[n * 64 + c];
    part[r][c] = acc;
    __syncthreads();
    if (r == 0) {
        float v = part[0][c] + part[1][c] + part[2][c] + part[3][c];
        pool[g * 64 + c] = v / fmaxf((float)(e - s), 1.f);
    }
}

// ---------------------------------------------------------------- MLP head (single block), FP32 out
__global__ __launch_bounds__(256) void k_mlp(const float* __restrict__ pool,
                                             const float* __restrict__ M0W,
                                             const float* __restrict__ M0b,
                                             const float* __restrict__ M1W,
                                             const float* __restrict__ M1b,
                                             float* __restrict__ out) {
    __shared__ float g[64][64];
    __shared__ float t1[64][64];
    int tid = threadIdx.x;
    for (int idx = tid; idx < 4096; idx += 256) {
        g[idx >> 6][idx & 63] = pool[idx];       // already averaged
    }
    __syncthreads();
    for (int idx = tid; idx < 4096; idx += 256) {
        int i = idx >> 6, j = idx & 63;
        float acc = M0b[j];
        for (int k = 0; k < 64; ++k) acc = fmaf(g[i][k], M0W[k * 64 + j], acc);
        t1[i][j] = fmaxf(acc, 0.f);
    }
    __syncthreads();
    for (int idx = tid; idx < NG * DOUT; idx += 256) {
        int i = idx / DOUT, j = idx % DOUT;
        float acc = M1b[j];
        for (int k = 0; k < 64; ++k) acc = fmaf(t1[i][k], M1W[k * DOUT + j], acc);
        out[idx] = acc;                          // fp32 output (reference output dtype)
    }
}

extern "C" void kernel_launch(void* const* d_in, const int* in_sizes, int n_in,
                              void* d_out, int out_size, void* d_ws, size_t ws_size,
                              hipStream_t stream) {
    const float* x   = (const float*)d_in[0];
    const int*   ei  = (const int*)d_in[1];
    const int*   bat = (const int*)d_in[2];
    const float* A_W = (const float*)d_in[3];
    const float* A_b = (const float*)d_in[4];
    const float* W0  = (const float*)d_in[5];
    const float* as0 = (const float*)d_in[6];
    const float* ad0 = (const float*)d_in[7];
    const float* b0  = (const float*)d_in[8];
    const float* W1  = (const float*)d_in[9];
    const float* as1 = (const float*)d_in[10];
    const float* ad1 = (const float*)d_in[11];
    const float* b1  = (const float*)d_in[12];
    const float* W2  = (const float*)d_in[13];
    const float* as2 = (const float*)d_in[14];
    const float* ad2 = (const float*)d_in[15];
    const float* b2  = (const float*)d_in[16];
    const float* M0W = (const float*)d_in[17];
    const float* M0b = (const float*)d_in[18];
    const float* M1W = (const float*)d_in[19];
    const float* M1b = (const float*)d_in[20];

    char* ws = (char*)d_ws;
    float*  hA      = (float*) (ws);                 // 51.2 MB f32 [NN,256] (agg out / gemm A)
    ushort* hB      = (ushort*)(ws + 51200000);      // 25.6 MB bf16 [NN,256] h_lin (gather source)
    float*  ss      = (float*) (ws + 102400000);     // [NN,4]
    float*  sd      = (float*) (ws + 103200000);     // [NN,4]
    int*    row_ptr = (int*)   (ws + 104000000);     // [NN+1]
    int*    cursor  = (int*)   (ws + 104200064);     // [NN] (also degree)
    int*    col_idx = (int*)   (ws + 104400128);     // [NEP]
    float*  pool    = (float*) (ws + 107800128);     // [NG,64]
    int*    gs      = (int*)   (ws + 107816512);     // [NG+1]

    const int EB = (NEP + 255) / 256;     // 3321

    // input projection
    k_lin0f<<<(NN * 64) / 256, 256, 0, stream>>>(x, A_W, A_b, hA);

    // CSR build (once per call)
    hipMemsetAsync(cursor, 0, NN * sizeof(int), stream);
    k_degree<<<EB, 256, 0, stream>>>(ei, cursor);
    k_scan<<<1, 256, 0, stream>>>(cursor, row_ptr);
    hipMemsetAsync(cursor, 0, NN * sizeof(int), stream);
    k_scatter<<<EB, 256, 0, stream>>>(ei, row_ptr, cursor, col_idx);

    dim3 ggrid(782, 4);
    // layer 0 (K=64)
    k_gemm<64><<<ggrid, 256, 0, stream>>>(hA, W0, hB, as0, ad0, ss, sd);
    k_agg<0><<<12500, 256, 0, stream>>>(hB, ss, sd, row_ptr, col_idx, b0, hA);
    // layer 1 (K=256)
    k_gemm<256><<<ggrid, 256, 0, stream>>>(hA, W1, hB, as1, ad1, ss, sd);
    k_agg<0><<<12500, 256, 0, stream>>>(hB, ss, sd, row_ptr, col_idx, b1, hA);
    // layer 2 (K=256, head-mean -> [NN,64] into hA)
    k_gemm<256><<<ggrid, 256, 0, stream>>>(hA, W2, hB, as2, ad2, ss, sd);
    k_agg<1><<<12500, 256, 0, stream>>>(hB, ss, sd, row_ptr, col_idx, b2, hA);

    // pooling + MLP head
    k_bounds<<<1, 64, 0, stream>>>(bat, gs);
    k_poolG<<<NG, 256, 0, stream>>>(hA, gs, pool);
    k_mlp<<<1, 256, 0, stream>>>(pool, M0W, M0b, M1W, M1b, (float*)d_out);
}

// Round 12
// 703.230 us; speedup vs baseline: 6.6059x; 1.1480x over previous
//
#include <hip/hip_runtime.h>
#include <hip/hip_bf16.h>

#define NN   50000
#define NE   800000
#define NEP  850000   // NE + NN self loops
#define NG   64
#define HH   256      // 4 heads * 64 ch
#define DOUT 10

typedef __attribute__((ext_vector_type(8))) short bf16x8;
typedef __attribute__((ext_vector_type(4))) float f32x4;

__device__ inline float bf2f(ushort u) {
    union { unsigned int i; float f; } v; v.i = ((unsigned int)u) << 16; return v.f;
}
__device__ inline ushort f2bf(float f) {   // round-to-nearest-even (finite)
    union { float f; unsigned int i; } v; v.f = f;
    unsigned int x = v.i;
    return (ushort)((x + 0x7FFFu + ((x >> 16) & 1u)) >> 16);
}

// ---------------------------------------------------------------- h0 = x@A_W + A_b -> bf16 [NN,64]
__global__ __launch_bounds__(256) void k_lin0b(const float* __restrict__ x,
                                               const float* __restrict__ W,
                                               const float* __restrict__ b,
                                               ushort* __restrict__ out) {
    int idx = blockIdx.x * 256 + threadIdx.x;   // grid exactly NN*64
    int n = idx >> 6, c = idx & 63;
    if (n >= NN) return;
    float acc = b[c];
    #pragma unroll
    for (int k = 0; k < 16; ++k) acc = fmaf(x[n * 16 + k], W[k * 64 + c], acc);
    out[idx] = f2bf(acc);
}

// ---------------------------------------------------------------- degree histogram (deg passed zeroed)
__global__ __launch_bounds__(256) void k_degree(const int* __restrict__ ei, int* __restrict__ deg) {
    int e = blockIdx.x * 256 + threadIdx.x;
    if (e >= NEP) return;
    int dst = (e < NE) ? ei[NE + e] : (e - NE);
    atomicAdd(&deg[dst], 1);
}

// ---------------------------------------------------------------- exclusive scan, 1 block x 256 thr
__global__ __launch_bounds__(256) void k_scan(const int* __restrict__ deg, int* __restrict__ row_ptr) {
    __shared__ int psum[256];
    const int CH = 196;                 // 256*196 = 50176 >= NN
    int tid = threadIdx.x;
    int lo = tid * CH;
    int hi = lo + CH; if (hi > NN) hi = NN;
    int s = 0;
    for (int i = lo; i < hi; ++i) s += deg[i];
    psum[tid] = s;
    __syncthreads();
    if (tid == 0) {
        int run = 0;
        for (int i = 0; i < 256; ++i) { int v = psum[i]; psum[i] = run; run += v; }
    }
    __syncthreads();
    int run = psum[tid];
    for (int i = lo; i < hi; ++i) { row_ptr[i] = run; run += deg[i]; }
    if (tid == 255) row_ptr[NN] = run;
}

// ---------------------------------------------------------------- CSR scatter (cursor passed zeroed)
__global__ __launch_bounds__(256) void k_scatter(const int* __restrict__ ei,
                                                 const int* __restrict__ row_ptr,
                                                 int* __restrict__ cursor,
                                                 int* __restrict__ col_idx) {
    int e = blockIdx.x * 256 + threadIdx.x;
    if (e >= NEP) return;
    int src, dst;
    if (e < NE) { src = ei[e]; dst = ei[NE + e]; }
    else        { src = e - NE; dst = e - NE; }
    int pos = atomicAdd(&cursor[dst], 1);
    col_idx[row_ptr[dst] + pos] = src;
}

// ---------------------------------------------------------------- W prep: fp32 [K,256] -> bf16 hi/lo col-major [256,K]
template <int K>
__global__ __launch_bounds__(256) void k_wprep(const float* __restrict__ W,
                                               ushort* __restrict__ Whi,
                                               ushort* __restrict__ Wlo) {
    int idx = blockIdx.x * 256 + threadIdx.x;   // grid exactly K*256/256
    int k = idx >> 8, col = idx & 255;
    float v = W[idx];
    ushort hi = f2bf(v);
    Whi[col * K + k] = hi;
    Wlo[col * K + k] = f2bf(v - bf2f(hi));      // residual: W ~ fp32-accurate as hi+lo
}

// ---------------------------------------------------------------- MFMA GEMM: C[NN,256](bf16) = A[NN,K](bf16) @ (Whi+Wlo)
// block = 64 rows x 256 cols, wave w = head w. Fused score epilogue from fp32 acc.
// MFMA conventions: C/D col=lane&15,row=(lane>>4)*4+reg [HW-verified]; A/B use same
// within-K elem rule (k=(l>>4)*8+e) for both operands -> permutation-safe.
template <int K>
__global__ __launch_bounds__(256) void k_gemm(const ushort* __restrict__ A,
                                              const ushort* __restrict__ Whi,
                                              const ushort* __restrict__ Wlo,
                                              ushort* __restrict__ C,
                                              const float* __restrict__ a_s,
                                              const float* __restrict__ a_d,
                                              float* __restrict__ ss,
                                              float* __restrict__ sd) {
    __shared__ ushort As[64][40];    // pad to 40 (80B, 20 words) -> ~2-way banks
    __shared__ ushort Bh[256][40];
    __shared__ ushort Bl[256][40];
    int tid = threadIdx.x;
    int w = tid >> 6, l = tid & 63;
    int rl = l & 15, rg = l >> 4;
    int m0 = blockIdx.x * 64;
    f32x4 acc[4][4];
    #pragma unroll
    for (int i = 0; i < 4; ++i)
        #pragma unroll
        for (int j = 0; j < 4; ++j) acc[i][j] = (f32x4){0.f, 0.f, 0.f, 0.f};

    int arow = tid >> 2, ak8 = (tid & 3) << 3;
    for (int k0 = 0; k0 < K; k0 += 32) {
        {   // stage A 64x32
            int gr = m0 + arow; if (gr >= NN) gr = NN - 1;
            *reinterpret_cast<bf16x8*>(&As[arow][ak8]) =
                *reinterpret_cast<const bf16x8*>(&A[gr * K + k0 + ak8]);
        }
        #pragma unroll
        for (int j = 0; j < 4; ++j) {   // stage B 256x32 hi+lo (thread=col)
            *reinterpret_cast<bf16x8*>(&Bh[tid][j << 3]) =
                *reinterpret_cast<const bf16x8*>(&Whi[tid * K + k0 + (j << 3)]);
            *reinterpret_cast<bf16x8*>(&Bl[tid][j << 3]) =
                *reinterpret_cast<const bf16x8*>(&Wlo[tid * K + k0 + (j << 3)]);
        }
        __syncthreads();
        int kg = rg << 3;
        bf16x8 a_frag[4], bh_frag[4], bl_frag[4];
        #pragma unroll
        for (int rt = 0; rt < 4; ++rt)
            a_frag[rt] = *reinterpret_cast<const bf16x8*>(&As[rt * 16 + rl][kg]);
        #pragma unroll
        for (int ct = 0; ct < 4; ++ct) {
            int col = (w << 6) + ct * 16 + rl;
            bh_frag[ct] = *reinterpret_cast<const bf16x8*>(&Bh[col][kg]);
            bl_frag[ct] = *reinterpret_cast<const bf16x8*>(&Bl[col][kg]);
        }
        #pragma unroll
        for (int rt = 0; rt < 4; ++rt)
            #pragma unroll
            for (int ct = 0; ct < 4; ++ct) {
                acc[rt][ct] = __builtin_amdgcn_mfma_f32_16x16x32_bf16(
                    a_frag[rt], bh_frag[ct], acc[rt][ct], 0, 0, 0);
                acc[rt][ct] = __builtin_amdgcn_mfma_f32_16x16x32_bf16(
                    a_frag[rt], bl_frag[ct], acc[rt][ct], 0, 0, 0);
            }
        __syncthreads();
    }
    // epilogue: bf16 C store + fused scores (fp32 acc)
    float as4[4], ad4[4];
    #pragma unroll
    for (int ct = 0; ct < 4; ++ct) {
        as4[ct] = a_s[(w << 6) + ct * 16 + rl];
        ad4[ct] = a_d[(w << 6) + ct * 16 + rl];
    }
    #pragma unroll
    for (int rt = 0; rt < 4; ++rt)
        #pragma unroll
        for (int reg = 0; reg < 4; ++reg) {
            int m = m0 + rt * 16 + (rg << 2) + reg;
            float ps = 0.f, pd = 0.f;
            #pragma unroll
            for (int ct = 0; ct < 4; ++ct) {
                float v = acc[rt][ct][reg];
                ps = fmaf(v, as4[ct], ps);
                pd = fmaf(v, ad4[ct], pd);
                if (m < NN) C[m * HH + (w << 6) + ct * 16 + rl] = f2bf(v);
            }
            #pragma unroll
            for (int d = 1; d < 16; d <<= 1) {
                ps += __shfl_xor(ps, d, 64);
                pd += __shfl_xor(pd, d, 64);
            }
            if (rl == 0 && m < NN) {
                ss[m * 4 + w] = ps;
                sd[m * 4 + w] = pd;
            }
        }
}

// ---------------------------------------------------------------- online-softmax aggregation, 1 WAVE/node
// MODE 0: concat + bias + elu -> bf16 [NN,256];  MODE 1: head-mean + bias -> f32 [NN,64]
template <int MODE>
__global__ __launch_bounds__(256) void k_agg(const ushort* __restrict__ hlin,
                                             const float* __restrict__ ss,
                                             const float* __restrict__ sd,
                                             const int* __restrict__ row_ptr,
                                             const int* __restrict__ col_idx,
                                             const float* __restrict__ bias,
                                             ushort* __restrict__ outb,
                                             float* __restrict__ outf) {
    int wid = threadIdx.x >> 6, lane = threadIdx.x & 63;
    int n = blockIdx.x * 4 + wid;                     // NN = 12500*4 exactly
    int h = lane >> 4, c4 = (lane & 15) << 2;
    int rs = row_ptr[n], re = row_ptr[n + 1];
    float sdn = sd[n * 4 + h];
    int sn = col_idx[rs];
    float sc = ss[sn * 4 + h] + sdn;
    sc = (sc > 0.f) ? sc : 0.2f * sc;                 // leaky_relu 0.2
    float m = sc, s = 1.f;
    ushort4 hv = *reinterpret_cast<const ushort4*>(&hlin[sn * HH + (h << 6) + c4]);
    float a0 = bf2f(hv.x), a1 = bf2f(hv.y), a2 = bf2f(hv.z), a3 = bf2f(hv.w);
    int e = rs + 1;
    for (; e + 1 < re; e += 2) {
        int sn0 = col_idx[e], sn1 = col_idx[e + 1];
        float t0 = ss[sn0 * 4 + h];
        float t1 = ss[sn1 * 4 + h];
        ushort4 u0 = *reinterpret_cast<const ushort4*>(&hlin[sn0 * HH + (h << 6) + c4]);
        ushort4 u1 = *reinterpret_cast<const ushort4*>(&hlin[sn1 * HH + (h << 6) + c4]);
        float s0 = t0 + sdn; s0 = (s0 > 0.f) ? s0 : 0.2f * s0;
        float mn = fmaxf(m, s0);
        float d  = __expf(fminf(m, s0) - mn);
        float cs = (s0 > m) ? d : 1.f;
        float ph = (s0 > m) ? 1.f : d;
        m = mn;
        s  = fmaf(s,  cs, ph);
        a0 = fmaf(a0, cs, ph * bf2f(u0.x));
        a1 = fmaf(a1, cs, ph * bf2f(u0.y));
        a2 = fmaf(a2, cs, ph * bf2f(u0.z));
        a3 = fmaf(a3, cs, ph * bf2f(u0.w));
        float s1 = t1 + sdn; s1 = (s1 > 0.f) ? s1 : 0.2f * s1;
        mn = fmaxf(m, s1);
        d  = __expf(fminf(m, s1) - mn);
        cs = (s1 > m) ? d : 1.f;
        ph = (s1 > m) ? 1.f : d;
        m = mn;
        s  = fmaf(s,  cs, ph);
        a0 = fmaf(a0, cs, ph * bf2f(u1.x));
        a1 = fmaf(a1, cs, ph * bf2f(u1.y));
        a2 = fmaf(a2, cs, ph * bf2f(u1.z));
        a3 = fmaf(a3, cs, ph * bf2f(u1.w));
    }
    if (e < re) {
        int sn0 = col_idx[e];
        float t0 = ss[sn0 * 4 + h];
        ushort4 u0 = *reinterpret_cast<const ushort4*>(&hlin[sn0 * HH + (h << 6) + c4]);
        float s0 = t0 + sdn; s0 = (s0 > 0.f) ? s0 : 0.2f * s0;
        float mn = fmaxf(m, s0);
        float d  = __expf(fminf(m, s0) - mn);
        float cs = (s0 > m) ? d : 1.f;
        float ph = (s0 > m) ? 1.f : d;
        s  = fmaf(s,  cs, ph);
        a0 = fmaf(a0, cs, ph * bf2f(u0.x));
        a1 = fmaf(a1, cs, ph * bf2f(u0.y));
        a2 = fmaf(a2, cs, ph * bf2f(u0.z));
        a3 = fmaf(a3, cs, ph * bf2f(u0.w));
    }
    float inv = 1.f / s;
    float o0 = a0 * inv, o1 = a1 * inv, o2 = a2 * inv, o3 = a3 * inv;
    if (MODE == 0) {
        o0 += bias[(h << 6) + c4 + 0];
        o1 += bias[(h << 6) + c4 + 1];
        o2 += bias[(h << 6) + c4 + 2];
        o3 += bias[(h << 6) + c4 + 3];
        o0 = (o0 > 0.f) ? o0 : (__expf(o0) - 1.f);    // elu
        o1 = (o1 > 0.f) ? o1 : (__expf(o1) - 1.f);
        o2 = (o2 > 0.f) ? o2 : (__expf(o2) - 1.f);
        o3 = (o3 > 0.f) ? o3 : (__expf(o3) - 1.f);
        ushort4 ob;
        ob.x = f2bf(o0); ob.y = f2bf(o1); ob.z = f2bf(o2); ob.w = f2bf(o3);
        *reinterpret_cast<ushort4*>(&outb[n * HH + (h << 6) + c4]) = ob;
    } else {
        o0 += __shfl_xor(o0, 16, 64); o0 += __shfl_xor(o0, 32, 64);
        o1 += __shfl_xor(o1, 16, 64); o1 += __shfl_xor(o1, 32, 64);
        o2 += __shfl_xor(o2, 16, 64); o2 += __shfl_xor(o2, 32, 64);
        o3 += __shfl_xor(o3, 16, 64); o3 += __shfl_xor(o3, 32, 64);
        if (h == 0) {
            float4 o = make_float4(0.25f * o0 + bias[c4 + 0],
                                   0.25f * o1 + bias[c4 + 1],
                                   0.25f * o2 + bias[c4 + 2],
                                   0.25f * o3 + bias[c4 + 3]);
            *reinterpret_cast<float4*>(&outf[n * 64 + c4]) = o;
        }
    }
}

// ---------------------------------------------------------------- graph boundaries in sorted batch
__global__ void k_bounds(const int* __restrict__ batch, int* __restrict__ gs) {
    int g = threadIdx.x;                         // 1 block, 64 threads
    if (g < NG) {
        int lo = 0, hi = NN;
        while (lo < hi) { int mid = (lo + hi) >> 1; if (batch[mid] < g) lo = mid + 1; else hi = mid; }
        gs[g] = lo;
    }
    if (g == 0) gs[NG] = NN;
}

// ---------------------------------------------------------------- mean pool, 1 block/graph, no atomics
__global__ __launch_bounds__(256) void k_poolG(const float* __restrict__ h,
                                               const int* __restrict__ gs,
                                               float* __restrict__ pool) {
    __shared__ float part[4][64];
    int g = blockIdx.x;
    int c = threadIdx.x & 63, r = threadIdx.x >> 6;
    int s = gs[g], e = gs[g + 1];
    float acc = 0.f;
    for (int n = s + r; n < e; n += 4) acc += h[n * 64 + c];
    part[r][c] = acc;
    __syncthreads();
    if (r == 0) {
        float v = part[0][c] + part[1][c] + part[2][c] + part[3][c];
        pool[g * 64 + c] = v / fmaxf((float)(e - s), 1.f);
    }
}

// ---------------------------------------------------------------- MLP head (single block), FP32 out
__global__ __launch_bounds__(256) void k_mlp(const float* __restrict__ pool,
                                             const float* __restrict__ M0W,
                                             const float* __restrict__ M0b,
                                             const float* __restrict__ M1W,
                                             const float* __restrict__ M1b,
                                             float* __restrict__ out) {
    __shared__ float g[64][64];
    __shared__ float t1[64][64];
    int tid = threadIdx.x;
    for (int idx = tid; idx < 4096; idx += 256) {
        g[idx >> 6][idx & 63] = pool[idx];       // already averaged
    }
    __syncthreads();
    for (int idx = tid; idx < 4096; idx += 256) {
        int i = idx >> 6, j = idx & 63;
        float acc = M0b[j];
        for (int k = 0; k < 64; ++k) acc = fmaf(g[i][k], M0W[k * 64 + j], acc);
        t1[i][j] = fmaxf(acc, 0.f);
    }
    __syncthreads();
    for (int idx = tid; idx < NG * DOUT; idx += 256) {
        int i = idx / DOUT, j = idx % DOUT;
        float acc = M1b[j];
        for (int k = 0; k < 64; ++k) acc = fmaf(t1[i][k], M1W[k * DOUT + j], acc);
        out[idx] = acc;                          // fp32 output (reference output dtype)
    }
}

extern "C" void kernel_launch(void* const* d_in, const int* in_sizes, int n_in,
                              void* d_out, int out_size, void* d_ws, size_t ws_size,
                              hipStream_t stream) {
    const float* x   = (const float*)d_in[0];
    const int*   ei  = (const int*)d_in[1];
    const int*   bat = (const int*)d_in[2];
    const float* A_W = (const float*)d_in[3];
    const float* A_b = (const float*)d_in[4];
    const float* W0  = (const float*)d_in[5];
    const float* as0 = (const float*)d_in[6];
    const float* ad0 = (const float*)d_in[7];
    const float* b0  = (const float*)d_in[8];
    const float* W1  = (const float*)d_in[9];
    const float* as1 = (const float*)d_in[10];
    const float* ad1 = (const float*)d_in[11];
    const float* b1  = (const float*)d_in[12];
    const float* W2  = (const float*)d_in[13];
    const float* as2 = (const float*)d_in[14];
    const float* ad2 = (const float*)d_in[15];
    const float* b2  = (const float*)d_in[16];
    const float* M0W = (const float*)d_in[17];
    const float* M0b = (const float*)d_in[18];
    const float* M1W = (const float*)d_in[19];
    const float* M1b = (const float*)d_in[20];

    char* ws = (char*)d_ws;
    ushort* hB_bf   = (ushort*)(ws);                 // 25.6 MB bf16 [NN,256] h_lin (GEMM C / gather src)
    ushort* hA_bf   = (ushort*)(ws + 25600000);      // 25.6 MB bf16 [NN,256] agg<0> out (GEMM A)
    ushort* h0_bf   = (ushort*)(ws + 51200000);      //  6.4 MB bf16 [NN,64]  input proj
    float*  h2      = (float*) (ws + 57600000);      // 12.8 MB f32  [NN,64]  agg<1> out
    float*  ss      = (float*) (ws + 70400000);      // [NN,4]
    float*  sd      = (float*) (ws + 71200000);      // [NN,4]
    int*    row_ptr = (int*)   (ws + 72000000);      // [NN+1]
    int*    cursor  = (int*)   (ws + 72200064);      // [NN] (also degree)
    int*    col_idx = (int*)   (ws + 72400128);      // [NEP]
    float*  pool    = (float*) (ws + 75800128);      // [NG,64]
    int*    gs      = (int*)   (ws + 75816512);      // [NG+1]
    ushort* Whi     = (ushort*)(ws + 75817536);      // 128 KB bf16 [256,K] col-major
    ushort* Wlo     = (ushort*)(ws + 75948608);      // 128 KB

    const int EB = (NEP + 255) / 256;     // 3321
    const int GB = (NN + 63) / 64;        // 782 gemm blocks

    // input projection (bf16 out)
    k_lin0b<<<(NN * 64) / 256, 256, 0, stream>>>(x, A_W, A_b, h0_bf);

    // CSR build (once per call)
    hipMemsetAsync(cursor, 0, NN * sizeof(int), stream);
    k_degree<<<EB, 256, 0, stream>>>(ei, cursor);
    k_scan<<<1, 256, 0, stream>>>(cursor, row_ptr);
    hipMemsetAsync(cursor, 0, NN * sizeof(int), stream);
    k_scatter<<<EB, 256, 0, stream>>>(ei, row_ptr, cursor, col_idx);

    // layer 0 (K=64)
    k_wprep<64><<<64, 256, 0, stream>>>(W0, Whi, Wlo);
    k_gemm<64><<<GB, 256, 0, stream>>>(h0_bf, Whi, Wlo, hB_bf, as0, ad0, ss, sd);
    k_agg<0><<<12500, 256, 0, stream>>>(hB_bf, ss, sd, row_ptr, col_idx, b0, hA_bf, nullptr);
    // layer 1 (K=256)
    k_wprep<256><<<256, 256, 0, stream>>>(W1, Whi, Wlo);
    k_gemm<256><<<GB, 256, 0, stream>>>(hA_bf, Whi, Wlo, hB_bf, as1, ad1, ss, sd);
    k_agg<0><<<12500, 256, 0, stream>>>(hB_bf, ss, sd, row_ptr, col_idx, b1, hA_bf, nullptr);
    // layer 2 (K=256, head-mean -> f32 [NN,64])
    k_wprep<256><<<256, 256, 0, stream>>>(W2, Whi, Wlo);
    k_gemm<256><<<GB, 256, 0, stream>>>(hA_bf, Whi, Wlo, hB_bf, as2, ad2, ss, sd);
    k_agg<1><<<12500, 256, 0, stream>>>(hB_bf, ss, sd, row_ptr, col_idx, b2, nullptr, h2);

    // pooling + MLP head
    k_bounds<<<1, 64, 0, stream>>>(bat, gs);
    k_poolG<<<NG, 256, 0, stream>>>(h2, gs, pool);
    k_mlp<<<1, 256, 0, stream>>>(pool, M0W, M0b, M1W, M1b, (float*)d_out);
}

// Round 13
// 624.888 us; speedup vs baseline: 7.4341x; 1.1254x over previous
//
#include <hip/hip_runtime.h>
#include <hip/hip_bf16.h>

#define NN   50000
#define NE   800000
#define NEP  850000   // NE + NN self loops
#define NG   64
#define HH   256      // 4 heads * 64 ch
#define DOUT 10
#define SCH  196      // scan chunk: 256*196 = 50176 >= NN

typedef __attribute__((ext_vector_type(8))) short bf16x8;
typedef __attribute__((ext_vector_type(4))) float f32x4;

__device__ inline float bf2f(ushort u) {
    union { unsigned int i; float f; } v; v.i = ((unsigned int)u) << 16; return v.f;
}
__device__ inline ushort f2bf(float f) {   // round-to-nearest-even (finite)
    union { float f; unsigned int i; } v; v.f = f;
    unsigned int x = v.i;
    return (ushort)((x + 0x7FFFu + ((x >> 16) & 1u)) >> 16);
}

// ---------------------------------------------------------------- h0 = x@A_W + A_b -> bf16 [NN,64]
__global__ __launch_bounds__(256) void k_lin0b(const float* __restrict__ x,
                                               const float* __restrict__ W,
                                               const float* __restrict__ b,
                                               ushort* __restrict__ out) {
    int idx = blockIdx.x * 256 + threadIdx.x;   // grid exactly NN*64
    int n = idx >> 6, c = idx & 63;
    if (n >= NN) return;
    float acc = b[c];
    #pragma unroll
    for (int k = 0; k < 16; ++k) acc = fmaf(x[n * 16 + k], W[k * 64 + c], acc);
    out[idx] = f2bf(acc);
}

// ---------------------------------------------------------------- degree histogram (deg passed zeroed)
__global__ __launch_bounds__(256) void k_degree(const int* __restrict__ ei, int* __restrict__ deg) {
    int e = blockIdx.x * 256 + threadIdx.x;
    if (e >= NEP) return;
    int dst = (e < NE) ? ei[NE + e] : (e - NE);
    atomicAdd(&deg[dst], 1);
}

// ---------------------------------------------------------------- 3-phase multi-block exclusive scan
// A: block b -> bsum[b] = sum of its 196-elem chunk
__global__ __launch_bounds__(256) void k_scanA(const int* __restrict__ deg, int* __restrict__ bsum) {
    __shared__ int wsum[4];
    int b = blockIdx.x, t = threadIdx.x, lane = t & 63, w = t >> 6;
    int i = b * SCH + t;
    int v = (t < SCH && i < NN) ? deg[i] : 0;
    #pragma unroll
    for (int d = 1; d < 64; d <<= 1) v += __shfl_xor(v, d, 64);
    if (lane == 0) wsum[w] = v;
    __syncthreads();
    if (t == 0) bsum[b] = wsum[0] + wsum[1] + wsum[2] + wsum[3];
}
// B: 1 block: boff = exclusive scan of bsum[256]; row_ptr[NN] = NEP (total is constant)
__global__ __launch_bounds__(256) void k_scanB(const int* __restrict__ bsum,
                                               int* __restrict__ boff,
                                               int* __restrict__ row_ptr) {
    __shared__ int wtot[4];
    int t = threadIdx.x, lane = t & 63, w = t >> 6;
    int v = bsum[t];
    int sc = v;
    #pragma unroll
    for (int d = 1; d < 64; d <<= 1) {
        int u = __shfl_up(sc, (unsigned)d, 64);
        if (lane >= d) sc += u;
    }
    if (lane == 63) wtot[w] = sc;
    __syncthreads();
    int woff = 0;
    #pragma unroll
    for (int k = 0; k < 4; ++k) woff += (k < w) ? wtot[k] : 0;
    boff[t] = woff + sc - v;                     // exclusive
    if (t == 0) row_ptr[NN] = NEP;
}
// C: block b: in-block exclusive scan of chunk + boff[b] -> row_ptr
__global__ __launch_bounds__(256) void k_scanC(const int* __restrict__ deg,
                                               const int* __restrict__ boff,
                                               int* __restrict__ row_ptr) {
    __shared__ int wtot[4];
    int b = blockIdx.x, t = threadIdx.x, lane = t & 63, w = t >> 6;
    int i = b * SCH + t;
    int v = (t < SCH && i < NN) ? deg[i] : 0;
    int sc = v;
    #pragma unroll
    for (int d = 1; d < 64; d <<= 1) {
        int u = __shfl_up(sc, (unsigned)d, 64);
        if (lane >= d) sc += u;
    }
    if (lane == 63) wtot[w] = sc;
    __syncthreads();
    int woff = 0;
    #pragma unroll
    for (int k = 0; k < 4; ++k) woff += (k < w) ? wtot[k] : 0;
    if (t < SCH && i < NN) row_ptr[i] = boff[b] + woff + sc - v;
}

// ---------------------------------------------------------------- CSR scatter (cursor passed zeroed)
__global__ __launch_bounds__(256) void k_scatter(const int* __restrict__ ei,
                                                 const int* __restrict__ row_ptr,
                                                 int* __restrict__ cursor,
                                                 int* __restrict__ col_idx) {
    int e = blockIdx.x * 256 + threadIdx.x;
    if (e >= NEP) return;
    int src, dst;
    if (e < NE) { src = ei[e]; dst = ei[NE + e]; }
    else        { src = e - NE; dst = e - NE; }
    int pos = atomicAdd(&cursor[dst], 1);
    col_idx[row_ptr[dst] + pos] = src;
}

// ---------------------------------------------------------------- W prep: fp32 [K,256] -> bf16 hi/lo col-major [256,K]
template <int K>
__global__ __launch_bounds__(256) void k_wprep(const float* __restrict__ W,
                                               ushort* __restrict__ Whi,
                                               ushort* __restrict__ Wlo) {
    int idx = blockIdx.x * 256 + threadIdx.x;   // grid exactly K*256/256
    int k = idx >> 8, col = idx & 255;
    float v = W[idx];
    ushort hi = f2bf(v);
    Whi[col * K + k] = hi;
    Wlo[col * K + k] = f2bf(v - bf2f(hi));      // residual: W ~ fp32-accurate as hi+lo
}

// ---------------------------------------------------------------- MFMA GEMM: C[NN,256](bf16) = A[NN,K](bf16) @ (Whi+Wlo)
// block = 64 rows x 256 cols, wave w = head w. Fused score epilogue from fp32 acc.
template <int K>
__global__ __launch_bounds__(256) void k_gemm(const ushort* __restrict__ A,
                                              const ushort* __restrict__ Whi,
                                              const ushort* __restrict__ Wlo,
                                              ushort* __restrict__ C,
                                              const float* __restrict__ a_s,
                                              const float* __restrict__ a_d,
                                              float* __restrict__ ss,
                                              float* __restrict__ sd) {
    __shared__ ushort As[64][40];    // pad to 40 -> ~2-way banks
    __shared__ ushort Bh[256][40];
    __shared__ ushort Bl[256][40];
    int tid = threadIdx.x;
    int w = tid >> 6, l = tid & 63;
    int rl = l & 15, rg = l >> 4;
    int m0 = blockIdx.x * 64;
    f32x4 acc[4][4];
    #pragma unroll
    for (int i = 0; i < 4; ++i)
        #pragma unroll
        for (int j = 0; j < 4; ++j) acc[i][j] = (f32x4){0.f, 0.f, 0.f, 0.f};

    int arow = tid >> 2, ak8 = (tid & 3) << 3;
    for (int k0 = 0; k0 < K; k0 += 32) {
        {   // stage A 64x32
            int gr = m0 + arow; if (gr >= NN) gr = NN - 1;
            *reinterpret_cast<bf16x8*>(&As[arow][ak8]) =
                *reinterpret_cast<const bf16x8*>(&A[gr * K + k0 + ak8]);
        }
        #pragma unroll
        for (int j = 0; j < 4; ++j) {   // stage B 256x32 hi+lo (thread=col)
            *reinterpret_cast<bf16x8*>(&Bh[tid][j << 3]) =
                *reinterpret_cast<const bf16x8*>(&Whi[tid * K + k0 + (j << 3)]);
            *reinterpret_cast<bf16x8*>(&Bl[tid][j << 3]) =
                *reinterpret_cast<const bf16x8*>(&Wlo[tid * K + k0 + (j << 3)]);
        }
        __syncthreads();
        int kg = rg << 3;
        bf16x8 a_frag[4], bh_frag[4], bl_frag[4];
        #pragma unroll
        for (int rt = 0; rt < 4; ++rt)
            a_frag[rt] = *reinterpret_cast<const bf16x8*>(&As[rt * 16 + rl][kg]);
        #pragma unroll
        for (int ct = 0; ct < 4; ++ct) {
            int col = (w << 6) + ct * 16 + rl;
            bh_frag[ct] = *reinterpret_cast<const bf16x8*>(&Bh[col][kg]);
            bl_frag[ct] = *reinterpret_cast<const bf16x8*>(&Bl[col][kg]);
        }
        #pragma unroll
        for (int rt = 0; rt < 4; ++rt)
            #pragma unroll
            for (int ct = 0; ct < 4; ++ct) {
                acc[rt][ct] = __builtin_amdgcn_mfma_f32_16x16x32_bf16(
                    a_frag[rt], bh_frag[ct], acc[rt][ct], 0, 0, 0);
                acc[rt][ct] = __builtin_amdgcn_mfma_f32_16x16x32_bf16(
                    a_frag[rt], bl_frag[ct], acc[rt][ct], 0, 0, 0);
            }
        __syncthreads();
    }
    // epilogue: bf16 C store + fused scores (fp32 acc)
    float as4[4], ad4[4];
    #pragma unroll
    for (int ct = 0; ct < 4; ++ct) {
        as4[ct] = a_s[(w << 6) + ct * 16 + rl];
        ad4[ct] = a_d[(w << 6) + ct * 16 + rl];
    }
    #pragma unroll
    for (int rt = 0; rt < 4; ++rt)
        #pragma unroll
        for (int reg = 0; reg < 4; ++reg) {
            int m = m0 + rt * 16 + (rg << 2) + reg;
            float ps = 0.f, pd = 0.f;
            #pragma unroll
            for (int ct = 0; ct < 4; ++ct) {
                float v = acc[rt][ct][reg];
                ps = fmaf(v, as4[ct], ps);
                pd = fmaf(v, ad4[ct], pd);
                if (m < NN) C[m * HH + (w << 6) + ct * 16 + rl] = f2bf(v);
            }
            #pragma unroll
            for (int d = 1; d < 16; d <<= 1) {
                ps += __shfl_xor(ps, d, 64);
                pd += __shfl_xor(pd, d, 64);
            }
            if (rl == 0 && m < NN) {
                ss[m * 4 + w] = ps;
                sd[m * 4 + w] = pd;
            }
        }
}

// ---------------------------------------------------------------- online-softmax aggregation, 1 WAVE/node
// MODE 0: concat + bias + elu -> bf16 [NN,256];  MODE 1: head-mean + bias -> f32 [NN,64]
template <int MODE>
__global__ __launch_bounds__(256) void k_agg(const ushort* __restrict__ hlin,
                                             const float* __restrict__ ss,
                                             const float* __restrict__ sd,
                                             const int* __restrict__ row_ptr,
                                             const int* __restrict__ col_idx,
                                             const float* __restrict__ bias,
                                             ushort* __restrict__ outb,
                                             float* __restrict__ outf) {
    int wid = threadIdx.x >> 6, lane = threadIdx.x & 63;
    int n = blockIdx.x * 4 + wid;                     // NN = 12500*4 exactly
    int h = lane >> 4, c4 = (lane & 15) << 2;
    int rs = row_ptr[n], re = row_ptr[n + 1];
    float sdn = sd[n * 4 + h];
    int sn = col_idx[rs];
    float sc = ss[sn * 4 + h] + sdn;
    sc = (sc > 0.f) ? sc : 0.2f * sc;                 // leaky_relu 0.2
    float m = sc, s = 1.f;
    ushort4 hv = *reinterpret_cast<const ushort4*>(&hlin[sn * HH + (h << 6) + c4]);
    float a0 = bf2f(hv.x), a1 = bf2f(hv.y), a2 = bf2f(hv.z), a3 = bf2f(hv.w);
    int e = rs + 1;
    for (; e + 1 < re; e += 2) {
        int sn0 = col_idx[e], sn1 = col_idx[e + 1];
        float t0 = ss[sn0 * 4 + h];
        float t1 = ss[sn1 * 4 + h];
        ushort4 u0 = *reinterpret_cast<const ushort4*>(&hlin[sn0 * HH + (h << 6) + c4]);
        ushort4 u1 = *reinterpret_cast<const ushort4*>(&hlin[sn1 * HH + (h << 6) + c4]);
        float s0 = t0 + sdn; s0 = (s0 > 0.f) ? s0 : 0.2f * s0;
        float mn = fmaxf(m, s0);
        float d  = __expf(fminf(m, s0) - mn);
        float cs = (s0 > m) ? d : 1.f;
        float ph = (s0 > m) ? 1.f : d;
        m = mn;
        s  = fmaf(s,  cs, ph);
        a0 = fmaf(a0, cs, ph * bf2f(u0.x));
        a1 = fmaf(a1, cs, ph * bf2f(u0.y));
        a2 = fmaf(a2, cs, ph * bf2f(u0.z));
        a3 = fmaf(a3, cs, ph * bf2f(u0.w));
        float s1 = t1 + sdn; s1 = (s1 > 0.f) ? s1 : 0.2f * s1;
        mn = fmaxf(m, s1);
        d  = __expf(fminf(m, s1) - mn);
        cs = (s1 > m) ? d : 1.f;
        ph = (s1 > m) ? 1.f : d;
        m = mn;
        s  = fmaf(s,  cs, ph);
        a0 = fmaf(a0, cs, ph * bf2f(u1.x));
        a1 = fmaf(a1, cs, ph * bf2f(u1.y));
        a2 = fmaf(a2, cs, ph * bf2f(u1.z));
        a3 = fmaf(a3, cs, ph * bf2f(u1.w));
    }
    if (e < re) {
        int sn0 = col_idx[e];
        float t0 = ss[sn0 * 4 + h];
        ushort4 u0 = *reinterpret_cast<const ushort4*>(&hlin[sn0 * HH + (h << 6) + c4]);
        float s0 = t0 + sdn; s0 = (s0 > 0.f) ? s0 : 0.2f * s0;
        float mn = fmaxf(m, s0);
        float d  = __expf(fminf(m, s0) - mn);
        float cs = (s0 > m) ? d : 1.f;
        float ph = (s0 > m) ? 1.f : d;
        s  = fmaf(s,  cs, ph);
        a0 = fmaf(a0, cs, ph * bf2f(u0.x));
        a1 = fmaf(a1, cs, ph * bf2f(u0.y));
        a2 = fmaf(a2, cs, ph * bf2f(u0.z));
        a3 = fmaf(a3, cs, ph * bf2f(u0.w));
    }
    float inv = 1.f / s;
    float o0 = a0 * inv, o1 = a1 * inv, o2 = a2 * inv, o3 = a3 * inv;
    if (MODE == 0) {
        o0 += bias[(h << 6) + c4 + 0];
        o1 += bias[(h << 6) + c4 + 1];
        o2 += bias[(h << 6) + c4 + 2];
        o3 += bias[(h << 6) + c4 + 3];
        o0 = (o0 > 0.f) ? o0 : (__expf(o0) - 1.f);    // elu
        o1 = (o1 > 0.f) ? o1 : (__expf(o1) - 1.f);
        o2 = (o2 > 0.f) ? o2 : (__expf(o2) - 1.f);
        o3 = (o3 > 0.f) ? o3 : (__expf(o3) - 1.f);
        ushort4 ob;
        ob.x = f2bf(o0); ob.y = f2bf(o1); ob.z = f2bf(o2); ob.w = f2bf(o3);
        *reinterpret_cast<ushort4*>(&outb[n * HH + (h << 6) + c4]) = ob;
    } else {
        o0 += __shfl_xor(o0, 16, 64); o0 += __shfl_xor(o0, 32, 64);
        o1 += __shfl_xor(o1, 16, 64); o1 += __shfl_xor(o1, 32, 64);
        o2 += __shfl_xor(o2, 16, 64); o2 += __shfl_xor(o2, 32, 64);
        o3 += __shfl_xor(o3, 16, 64); o3 += __shfl_xor(o3, 32, 64);
        if (h == 0) {
            float4 o = make_float4(0.25f * o0 + bias[c4 + 0],
                                   0.25f * o1 + bias[c4 + 1],
                                   0.25f * o2 + bias[c4 + 2],
                                   0.25f * o3 + bias[c4 + 3]);
            *reinterpret_cast<float4*>(&outf[n * 64 + c4]) = o;
        }
    }
}

// ---------------------------------------------------------------- graph boundaries in sorted batch
__global__ void k_bounds(const int* __restrict__ batch, int* __restrict__ gs) {
    int g = threadIdx.x;                         // 1 block, 64 threads
    if (g < NG) {
        int lo = 0, hi = NN;
        while (lo < hi) { int mid = (lo + hi) >> 1; if (batch[mid] < g) lo = mid + 1; else hi = mid; }
        gs[g] = lo;
    }
    if (g == 0) gs[NG] = NN;
}

// ---------------------------------------------------------------- mean pool, 1 block/graph, no atomics
__global__ __launch_bounds__(256) void k_poolG(const float* __restrict__ h,
                                               const int* __restrict__ gs,
                                               float* __restrict__ pool) {
    __shared__ float part[4][64];
    int g = blockIdx.x;
    int c = threadIdx.x & 63, r = threadIdx.x >> 6;
    int s = gs[g], e = gs[g + 1];
    float acc = 0.f;
    for (int n = s + r; n < e; n += 4) acc += h[n * 64 + c];
    part[r][c] = acc;
    __syncthreads();
    if (r == 0) {
        float v = part[0][c] + part[1][c] + part[2][c] + part[3][c];
        pool[g * 64 + c] = v / fmaxf((float)(e - s), 1.f);
    }
}

// ---------------------------------------------------------------- MLP head (single block), FP32 out
__global__ __launch_bounds__(256) void k_mlp(const float* __restrict__ pool,
                                             const float* __restrict__ M0W,
                                             const float* __restrict__ M0b,
                                             const float* __restrict__ M1W,
                                             const float* __restrict__ M1b,
                                             float* __restrict__ out) {
    __shared__ float g[64][64];
    __shared__ float t1[64][64];
    int tid = threadIdx.x;
    for (int idx = tid; idx < 4096; idx += 256) {
        g[idx >> 6][idx & 63] = pool[idx];       // already averaged
    }
    __syncthreads();
    for (int idx = tid; idx < 4096; idx += 256) {
        int i = idx >> 6, j = idx & 63;
        float acc = M0b[j];
        for (int k = 0; k < 64; ++k) acc = fmaf(g[i][k], M0W[k * 64 + j], acc);
        t1[i][j] = fmaxf(acc, 0.f);
    }
    __syncthreads();
    for (int idx = tid; idx < NG * DOUT; idx += 256) {
        int i = idx / DOUT, j = idx % DOUT;
        float acc = M1b[j];
        for (int k = 0; k < 64; ++k) acc = fmaf(t1[i][k], M1W[k * DOUT + j], acc);
        out[idx] = acc;                          // fp32 output (reference output dtype)
    }
}

extern "C" void kernel_launch(void* const* d_in, const int* in_sizes, int n_in,
                              void* d_out, int out_size, void* d_ws, size_t ws_size,
                              hipStream_t stream) {
    const float* x   = (const float*)d_in[0];
    const int*   ei  = (const int*)d_in[1];
    const int*   bat = (const int*)d_in[2];
    const float* A_W = (const float*)d_in[3];
    const float* A_b = (const float*)d_in[4];
    const float* W0  = (const float*)d_in[5];
    const float* as0 = (const float*)d_in[6];
    const float* ad0 = (const float*)d_in[7];
    const float* b0  = (const float*)d_in[8];
    const float* W1  = (const float*)d_in[9];
    const float* as1 = (const float*)d_in[10];
    const float* ad1 = (const float*)d_in[11];
    const float* b1  = (const float*)d_in[12];
    const float* W2  = (const float*)d_in[13];
    const float* as2 = (const float*)d_in[14];
    const float* ad2 = (const float*)d_in[15];
    const float* b2  = (const float*)d_in[16];
    const float* M0W = (const float*)d_in[17];
    const float* M0b = (const float*)d_in[18];
    const float* M1W = (const float*)d_in[19];
    const float* M1b = (const float*)d_in[20];

    char* ws = (char*)d_ws;
    ushort* hB_bf   = (ushort*)(ws);                 // 25.6 MB bf16 [NN,256] h_lin (GEMM C / gather src)
    ushort* hA_bf   = (ushort*)(ws + 25600000);      // 25.6 MB bf16 [NN,256] agg<0> out (GEMM A)
    ushort* h0_bf   = (ushort*)(ws + 51200000);      //  6.4 MB bf16 [NN,64]  input proj
    float*  h2      = (float*) (ws + 57600000);      // 12.8 MB f32  [NN,64]  agg<1> out
    float*  ss      = (float*) (ws + 70400000);      // [NN,4]
    float*  sd      = (float*) (ws + 71200000);      // [NN,4]
    int*    row_ptr = (int*)   (ws + 72000000);      // [NN+1]
    int*    cursor  = (int*)   (ws + 72200064);      // [NN] (also degree)
    int*    col_idx = (int*)   (ws + 72400128);      // [NEP]
    float*  pool    = (float*) (ws + 75800128);      // [NG,64]
    int*    gs      = (int*)   (ws + 75816512);      // [NG+1]
    ushort* Whi     = (ushort*)(ws + 75817536);      // 128 KB bf16 [256,K] col-major
    ushort* Wlo     = (ushort*)(ws + 75948608);      // 128 KB
    int*    bsum    = (int*)   (ws + 76079680);      // [256] scan block sums
    int*    boff    = (int*)   (ws + 76080704);      // [256] scan block offsets

    const int EB = (NEP + 255) / 256;     // 3321
    const int GB = (NN + 63) / 64;        // 782 gemm blocks

    // input projection (bf16 out)
    k_lin0b<<<(NN * 64) / 256, 256, 0, stream>>>(x, A_W, A_b, h0_bf);

    // CSR build (once per call) — multi-block 3-phase scan
    hipMemsetAsync(cursor, 0, NN * sizeof(int), stream);
    k_degree<<<EB, 256, 0, stream>>>(ei, cursor);
    k_scanA<<<256, 256, 0, stream>>>(cursor, bsum);
    k_scanB<<<1, 256, 0, stream>>>(bsum, boff, row_ptr);
    k_scanC<<<256, 256, 0, stream>>>(cursor, boff, row_ptr);
    hipMemsetAsync(cursor, 0, NN * sizeof(int), stream);
    k_scatter<<<EB, 256, 0, stream>>>(ei, row_ptr, cursor, col_idx);

    // layer 0 (K=64)
    k_wprep<64><<<64, 256, 0, stream>>>(W0, Whi, Wlo);
    k_gemm<64><<<GB, 256, 0, stream>>>(h0_bf, Whi, Wlo, hB_bf, as0, ad0, ss, sd);
    k_agg<0><<<12500, 256, 0, stream>>>(hB_bf, ss, sd, row_ptr, col_idx, b0, hA_bf, nullptr);
    // layer 1 (K=256)
    k_wprep<256><<<256, 256, 0, stream>>>(W1, Whi, Wlo);
    k_gemm<256><<<GB, 256, 0, stream>>>(hA_bf, Whi, Wlo, hB_bf, as1, ad1, ss, sd);
    k_agg<0><<<12500, 256, 0, stream>>>(hB_bf, ss, sd, row_ptr, col_idx, b1, hA_bf, nullptr);
    // layer 2 (K=256, head-mean -> f32 [NN,64])
    k_wprep<256><<<256, 256, 0, stream>>>(W2, Whi, Wlo);
    k_gemm<256><<<GB, 256, 0, stream>>>(hA_bf, Whi, Wlo, hB_bf, as2, ad2, ss, sd);
    k_agg<1><<<12500, 256, 0, stream>>>(hB_bf, ss, sd, row_ptr, col_idx, b2, nullptr, h2);

    // pooling + MLP head
    k_bounds<<<1, 64, 0, stream>>>(bat, gs);
    k_poolG<<<NG, 256, 0, stream>>>(h2, gs, pool);
    k_mlp<<<1, 256, 0, stream>>>(pool, M0W, M0b, M1W, M1b, (float*)d_out);
}